// Round 5
// baseline (3163.000 us; speedup 1.0000x reference)
//
#include <hip/hip_runtime.h>
#include <hip/hip_bf16.h>
#include <math.h>

// ---------------- problem constants ----------------
#define B_   8
#define T_   12
#define N_   325
#define C_   64
#define NT   3900     // N_*T_
#define LSP  328      // padded row stride of transposed sp matrix

__device__ __forceinline__ float sigm(float x) { return 1.f / (1.f + expf(-x)); }

__device__ __forceinline__ float blk_sum(float v, float* red) {
#pragma unroll
  for (int off = 1; off < 64; off <<= 1) v += __shfl_xor(v, off, 64);
  const int tid = threadIdx.x;
  __syncthreads();                 // protect red from previous use
  if ((tid & 63) == 0) red[tid >> 6] = v;
  __syncthreads();
  return red[0] + red[1] + red[2] + red[3];
}

// ---------------- sentinel (ws too small diagnostic) ----------------
__global__ __launch_bounds__(256) void k_sentinel(float* out, int n) {
  int i = blockIdx.x * 256 + threadIdx.x;
  if (i < n) out[i] = 7.0f;
}

// ---------------- k0: transpose sp (padded) ----------------
__global__ __launch_bounds__(256) void k0_convert(const float* __restrict__ sp,
                                                  float* __restrict__ LsT) {
  int idx = blockIdx.x * 256 + threadIdx.x;
  if (idx < N_ * LSP) {
    int m = idx / LSP, n = idx - m * LSP;
    LsT[idx] = (n < N_) ? sp[n * N_ + m] : 0.f;   // LsT[m][n] = Ls[n][m]
  }
}

// ---------------- k1: embeddings + theta coefficients ----------------
__global__ __launch_bounds__(256) void k1_embed(
    const int* __restrict__ TE, const float* __restrict__ SE,
    const float* __restrict__ w1, const float* __restrict__ b1,
    const float* __restrict__ w2, const float* __restrict__ b2,
    const float* __restrict__ sw1, const float* __restrict__ sb1,
    const float* __restrict__ sw2, const float* __restrict__ sb2,
    const float* __restrict__ t1w, const float* __restrict__ t1b,
    const float* __restrict__ t2w, const float* __restrict__ t2b,
    float* __restrict__ coef) {
  __shared__ float te2[8][10][12];
  __shared__ float ste[8][5][10];
  __shared__ float se1[5][10];
  __shared__ float se2[5][10];
  __shared__ float th[8][6][10];
  __shared__ int te64;
  const int tid = threadIdx.x;
  // Detect int64-encoded TE (harness-dependent): high words all zero.
  if (tid == 0) {
    int nz = 0;
    for (int k2 = 0; k2 < 96; k2++) nz += (TE[2 * k2 + 1] != 0) ? 1 : 0;
    te64 = (nz == 0) ? 1 : 0;
  }
  __syncthreads();
  for (int idx = tid; idx < 960; idx += 256) {
    int t = idx % 12, o = (idx / 12) % 10, b = idx / 120;
    int q = (b * 12 + t) * 2;
    int d = (te64 ? TE[2 * q] : TE[q]) % 7;
    int h = (te64 ? TE[2 * q + 2] : TE[q + 1]) % 288;
    float v = w1[o * 295 + d] + w1[o * 295 + 7 + h] + b1[o];
    te2[b][o][t] = fmaxf(v, 0.f);
  }
  __syncthreads();
  for (int idx = tid; idx < 400; idx += 256) {
    int s = idx % 10, o = (idx / 10) % 5, b = idx / 50;
    float a = b2[o];
    for (int t = 0; t < 12; t++) a += te2[b][s][t] * w2[o * 12 + t];
    ste[b][o][s] = fmaxf(a, 0.f);
  }
  if (tid < 50) {
    int o = tid / 10, j = tid % 10;
    float a = sb1[o];
    for (int n = 0; n < N_; n++) a += sw1[o * N_ + n] * SE[n * 10 + j];
    se1[o][j] = fmaxf(a, 0.f);
  }
  __syncthreads();
  if (tid < 50) {
    int t = tid / 10, s = tid % 10;
    float a = sb2[s];
    for (int j = 0; j < 10; j++) a += sw2[s * 10 + j] * se1[t][j];
    se2[t][s] = fmaxf(a, 0.f);
  }
  __syncthreads();
  for (int idx = tid; idx < 400; idx += 256) {
    int s = idx % 10, o = (idx / 10) % 5, b = idx / 50;
    ste[b][o][s] = fmaxf(se2[o][s] + ste[b][o][s], 0.f);
  }
  __syncthreads();
  for (int l = 0; l < 2; l++) {
    for (int idx = tid; idx < 480; idx += 256) {
      int s = idx % 10, q = (idx / 10) % 6, b = idx / 60;
      float a = t1b[l * 6 + q];
      for (int t = 0; t < 5; t++) a += ste[b][t][s] * t1w[(l * 6 + q) * 5 + t];
      th[b][q][s] = a;
    }
    __syncthreads();
    for (int idx = tid; idx < 528; idx += 256) {
      int q = idx % 6, p = (idx / 6) % 11, b = idx / 66;
      float a = t2b[l * 11 + p];
      for (int s = 0; s < 10; s++) a += th[b][q][s] * t2w[(l * 11 + p) * 10 + s];
      coef[(l * 8 + b) * 66 + q * 11 + p] = fmaxf(a, 0.f);
    }
    __syncthreads();
  }
}

// ---------------- k2: start 1x1 conv ----------------
__global__ __launch_bounds__(256) void k2_start(const float* __restrict__ src,
                                                const float* __restrict__ w,
                                                const float* __restrict__ bia,
                                                float* __restrict__ x) {
  int idx = blockIdx.x * 256 + threadIdx.x;
  if (idx >= B_ * C_ * NT) return;
  int pos = idx % NT, r = idx / NT, c = r & 63, b = r >> 6;
  int n = pos / 12, t = pos - 12 * n;
  float s = src[(b * 12 + t) * N_ + n];
  x[idx] = s * w[c] + bia[c];
}

// ---------------- k3: fused basis recursion + x_st accumulation ----------------
// one block per (b,c) slice; thread owns elements e = tid + 256k.
__global__ __launch_bounds__(256) void k3_basis(
    const float* __restrict__ x, const float* __restrict__ LsT,
    const float* __restrict__ tp, const float* __restrict__ coef,
    float* __restrict__ xst, float* __restrict__ gAll, float* __restrict__ gBll) {
  __shared__ float sL[3][NT];
  __shared__ float ltS[144];
  __shared__ float red[4];
  const int tid = threadIdx.x;
  const int bc = blockIdx.x;
  const float* cf = coef + (bc >> 6) * 66;
  const float* xs = x + (size_t)bc * NT;
  float* xo = xst + (size_t)bc * NT;
  float* gCur = gAll + (size_t)bc * NT;
  float* gPrev = gBll + (size_t)bc * NT;
  if (tid < 144) ltS[tid] = tp[tid];

  int nn[16], uu[16];
  float acc[16], rr[16], lastv[16];
#pragma unroll
  for (int k = 0; k < 16; k++) {
    int e = tid + (k << 8);
    nn[k] = e / 12;
    uu[k] = e - 12 * nn[k];
    acc[k] = 0.f;
  }

  // ---- m00 = unit(residual slice) ----
  float ss = 0.f;
#pragma unroll
  for (int k = 0; k < 16; k++) {
    int e = tid + (k << 8);
    float v = (e < NT) ? xs[e] : 0.f;
    rr[k] = v;
    ss += v * v;
  }
  ss = blk_sum(ss, red);
  {
    const float inv = 1.f / fmaxf(sqrtf(ss), 1e-8f);
    const float c0 = cf[0];
#pragma unroll
    for (int k = 0; k < 16; k++) {
      int e = tid + (k << 8);
      if (e < NT) {
        float v = rr[k] * inv;
        sL[0][e] = v;
        gCur[e] = v;
        acc[k] += c0 * v;
      }
    }
  }
  __syncthreads();

  int lt = 0, st = -1, m = 1;
  for (int i = 0; i <= 10; i++) {
    if (i > 0) {
      // ---------- spatial basis step: last_s = gCur, sec_s = gPrev ----------
      for (int e = tid; e < NT; e += 256) sL[0][e] = gCur[e];
      __syncthreads();
      float d1p = 0.f;
#pragma unroll
      for (int k = 0; k < 16; k++) {
        int e = tid + (k << 8);
        float r = 0.f;
        if (e < NT) {
          const int n = nn[k], u = uu[k];
          for (int mm = 0; mm < N_; mm++)
            r += LsT[mm * LSP + n] * sL[0][mm * 12 + u];
          lastv[k] = sL[0][e];
          d1p += r * lastv[k];
        }
        rr[k] = r;
      }
      const float d1 = blk_sum(d1p, red);
      float d2p = 0.f;
#pragma unroll
      for (int k = 0; k < 16; k++) {
        int e = tid + (k << 8);
        if (e < NT) {
          rr[k] -= d1 * lastv[k];
          if (i >= 2) d2p += rr[k] * gPrev[e];
        }
      }
      if (i >= 2) {   // sequential second projection (reference order)
        const float d2 = blk_sum(d2p, red);
#pragma unroll
        for (int k = 0; k < 16; k++) {
          int e = tid + (k << 8);
          if (e < NT) rr[k] -= d2 * gPrev[e];
        }
      }
      float np = 0.f;
#pragma unroll
      for (int k = 0; k < 16; k++) {
        int e = tid + (k << 8);
        if (e < NT) np += rr[k] * rr[k];
      }
      np = blk_sum(np, red);
      const float inv = 1.f / fmaxf(sqrtf(np), 1e-8f);
      const float c = cf[m]; m++;
#pragma unroll
      for (int k = 0; k < 16; k++) {
        int e = tid + (k << 8);
        if (e < NT) {
          float v = rr[k] * inv;
          sL[1][e] = v;
          gPrev[e] = v;
          acc[k] += c * v;
        }
      }
      { float* t2 = gCur; gCur = gPrev; gPrev = t2; }
      lt = 1; st = -1;
      __syncthreads();
    }
    // ---------- temporal chain (5 steps) ----------
    for (int j5 = 0; j5 < 5; j5++) {
      const int tg = (st < 0) ? ((lt + 1) % 3) : (3 - lt - st);
      float d1p = 0.f;
#pragma unroll
      for (int k = 0; k < 16; k++) {
        int e = tid + (k << 8);
        float r = 0.f;
        if (e < NT) {
          const float* Lrow = &sL[lt][nn[k] * 12];
          const int u = uu[k];
#pragma unroll
          for (int t = 0; t < 12; t++) r += Lrow[t] * ltS[t * 12 + u];
          lastv[k] = Lrow[u];
          d1p += r * lastv[k];
        }
        rr[k] = r;
      }
      const float d1 = blk_sum(d1p, red);
      float d2p = 0.f;
#pragma unroll
      for (int k = 0; k < 16; k++) {
        int e = tid + (k << 8);
        if (e < NT) {
          rr[k] -= d1 * lastv[k];
          if (st >= 0) d2p += rr[k] * sL[st][e];
        }
      }
      if (st >= 0) {
        const float d2 = blk_sum(d2p, red);
#pragma unroll
        for (int k = 0; k < 16; k++) {
          int e = tid + (k << 8);
          if (e < NT) rr[k] -= d2 * sL[st][e];
        }
      }
      float np = 0.f;
#pragma unroll
      for (int k = 0; k < 16; k++) {
        int e = tid + (k << 8);
        if (e < NT) np += rr[k] * rr[k];
      }
      np = blk_sum(np, red);
      const float inv = 1.f / fmaxf(sqrtf(np), 1e-8f);
      const float c = cf[m]; m++;
#pragma unroll
      for (int k = 0; k < 16; k++) {
        int e = tid + (k << 8);
        if (e < NT) {
          float v = rr[k] * inv;
          sL[tg][e] = v;
          acc[k] += c * v;
        }
      }
      st = lt; lt = tg;
      __syncthreads();
    }
  }
#pragma unroll
  for (int k = 0; k < 16; k++) {
    int e = tid + (k << 8);
    if (e < NT) xo[e] = acc[k];
  }
}

// ---------------- k4: st_mlp + bn -> hidden ----------------
__global__ __launch_bounds__(256) void k4_stmlp(
    const float* __restrict__ x, const float* __restrict__ xst,
    const float* __restrict__ W, const float* __restrict__ bias,
    const float* __restrict__ g, const float* __restrict__ bb,
    const float* __restrict__ bm, const float* __restrict__ bv,
    float* __restrict__ hid) {
  int idx = blockIdx.x * 256 + threadIdx.x;
  if (idx >= B_ * 16 * NT) return;
  int pos = idx % NT, r = idx / NT, og = r & 15, b = r >> 4;
  const float* xb = x + (size_t)b * 64 * NT + pos;
  const float* xsb = xst + (size_t)b * 64 * NT + pos;
  float a0 = 0, a1 = 0, a2 = 0, a3 = 0;
  for (int i = 0; i < 64; i++) {
    float h = xb[(size_t)i * NT];
    a0 += h * W[(og) * 128 + i];
    a1 += h * W[(og + 16) * 128 + i];
    a2 += h * W[(og + 32) * 128 + i];
    a3 += h * W[(og + 48) * 128 + i];
  }
  for (int i = 0; i < 64; i++) {
    float h = xsb[(size_t)i * NT];
    a0 += h * W[(og) * 128 + 64 + i];
    a1 += h * W[(og + 16) * 128 + 64 + i];
    a2 += h * W[(og + 32) * 128 + 64 + i];
    a3 += h * W[(og + 48) * 128 + 64 + i];
  }
  float accs[4] = {a0, a1, a2, a3};
#pragma unroll
  for (int k = 0; k < 4; k++) {
    int o = og + 16 * k;
    float y = accs[k] + bias[o];
    float sc = g[o] / sqrtf(bv[o] + 1e-5f);
    hid[((size_t)b * 64 + o) * NT + pos] = (y - bm[o]) * sc + bb[o];
  }
}

// ---------------- k5a: pyr1 gated ----------------
__global__ __launch_bounds__(256) void k5a_pyr1(const float* __restrict__ hid,
                                                const float* __restrict__ W,
                                                const float* __restrict__ bias,
                                                float* __restrict__ g1) {
  int idx = blockIdx.x * 256 + threadIdx.x;
  if (idx >= B_ * 32 * NT) return;
  int pos = idx % NT, r = idx / NT, cg = r & 31, b = r >> 5;
  const float* hb = hid + (size_t)b * 64 * NT + pos;
  float s0 = 0, u0 = 0, s1 = 0, u1 = 0;
  for (int i = 0; i < 64; i++) {
    float h = hb[(size_t)i * NT];
    s0 += h * W[(cg) * 64 + i];
    u0 += h * W[(cg + 64) * 64 + i];
    s1 += h * W[(cg + 32) * 64 + i];
    u1 += h * W[(cg + 96) * 64 + i];
  }
  g1[((size_t)b * 64 + cg) * NT + pos] =
      sigm(s0 + bias[cg]) * tanhf(u0 + bias[cg + 64]);
  g1[((size_t)b * 64 + cg + 32) * NT + pos] =
      sigm(s1 + bias[cg + 32]) * tanhf(u1 + bias[cg + 96]);
}

// ---------------- k5b: pyr2 gated ----------------
__global__ __launch_bounds__(256) void k5b_pyr2(const float* __restrict__ hid,
                                                const float* __restrict__ W,
                                                const float* __restrict__ bias,
                                                float* __restrict__ g2) {
  int idx = blockIdx.x * 256 + threadIdx.x;
  if (idx >= B_ * 32 * N_ * 4) return;
  int q = idx & 3, r = idx >> 2;
  int n = r % N_; r /= N_;
  int cg = r & 31, b = r >> 5;
  const float* hb = hid + (size_t)b * 64 * NT + n * 12 + 3 * q;
  float s0 = 0, u0 = 0, s1 = 0, u1 = 0;
  for (int i = 0; i < 64; i++) {
    const float* hh = hb + (size_t)i * NT;
#pragma unroll
    for (int k = 0; k < 3; k++) {
      float h = hh[k];
      s0 += h * W[(cg) * 192 + i * 3 + k];
      u0 += h * W[(cg + 64) * 192 + i * 3 + k];
      s1 += h * W[(cg + 32) * 192 + i * 3 + k];
      u1 += h * W[(cg + 96) * 192 + i * 3 + k];
    }
  }
  g2[(((size_t)b * 64 + cg) * N_ + n) * 4 + q] =
      sigm(s0 + bias[cg]) * tanhf(u0 + bias[cg + 64]);
  g2[(((size_t)b * 64 + cg + 32) * N_ + n) * 4 + q] =
      sigm(s1 + bias[cg + 32]) * tanhf(u1 + bias[cg + 96]);
}

// ---------------- k5c: pyr3 gated ----------------
__global__ __launch_bounds__(256) void k5c_pyr3(const float* __restrict__ hid,
                                                const float* __restrict__ W,
                                                const float* __restrict__ bias,
                                                float* __restrict__ g3) {
  int idx = blockIdx.x * 256 + threadIdx.x;
  if (idx >= B_ * 32 * N_ * 2) return;
  int q = idx & 1, r = idx >> 1;
  int n = r % N_; r /= N_;
  int cg = r & 31, b = r >> 5;
  const float* hb = hid + (size_t)b * 64 * NT + n * 12 + 6 * q;
  float s0 = 0, u0 = 0, s1 = 0, u1 = 0;
  for (int i = 0; i < 64; i++) {
    const float* hh = hb + (size_t)i * NT;
#pragma unroll
    for (int k = 0; k < 6; k++) {
      float h = hh[k];
      s0 += h * W[(cg) * 384 + i * 6 + k];
      u0 += h * W[(cg + 64) * 384 + i * 6 + k];
      s1 += h * W[(cg + 32) * 384 + i * 6 + k];
      u1 += h * W[(cg + 96) * 384 + i * 6 + k];
    }
  }
  g3[(((size_t)b * 64 + cg) * N_ + n) * 2 + q] =
      sigm(s0 + bias[cg]) * tanhf(u0 + bias[cg + 64]);
  g3[(((size_t)b * 64 + cg + 32) * N_ + n) * 2 + q] =
      sigm(s1 + bias[cg + 32]) * tanhf(u1 + bias[cg + 96]);
}

// ---------------- k5d: fusion conv + bn + residual bn ----------------
__global__ __launch_bounds__(256) void k5d_fuse(
    const float* __restrict__ g1, const float* __restrict__ g2, const float* __restrict__ g3,
    const float* __restrict__ W, const float* __restrict__ bias,
    const float* __restrict__ pg, const float* __restrict__ pb,
    const float* __restrict__ pm, const float* __restrict__ pv,
    const float* __restrict__ bg, const float* __restrict__ bb2,
    const float* __restrict__ bm2, const float* __restrict__ bv2,
    float* __restrict__ fus, float* __restrict__ x) {
  int idx = blockIdx.x * 256 + threadIdx.x;
  if (idx >= B_ * 16 * NT) return;
  int pos = idx % NT, r = idx / NT, og = r & 15, b = r >> 4;
  int n = pos / 12, t = pos - 12 * n;
  float a0 = 0, a1 = 0, a2 = 0, a3 = 0;
  const float* g1b = g1 + (size_t)b * 64 * NT + pos;
  for (int c = 0; c < 64; c++) {
    float v = g1b[(size_t)c * NT];
    a0 += v * W[(og) * 192 + c];
    a1 += v * W[(og + 16) * 192 + c];
    a2 += v * W[(og + 32) * 192 + c];
    a3 += v * W[(og + 48) * 192 + c];
  }
  float c4 = fminf(fmaxf((t - 1) * (1.f / 3.f), 0.f), 3.f);
  int q0 = (int)c4;
  float f4 = c4 - (float)q0;
  int q1 = min(q0 + 1, 3);
  const float* g2b = g2 + ((size_t)b * 64 * N_ + n) * 4;
  for (int c = 0; c < 64; c++) {
    float v = (1.f - f4) * g2b[c * (N_ * 4) + q0] + f4 * g2b[c * (N_ * 4) + q1];
    a0 += v * W[(og) * 192 + 64 + c];
    a1 += v * W[(og + 16) * 192 + 64 + c];
    a2 += v * W[(og + 32) * 192 + 64 + c];
    a3 += v * W[(og + 48) * 192 + 64 + c];
  }
  float f2 = fminf(fmaxf((2 * t - 5) * (1.f / 12.f), 0.f), 1.f);
  const float* g3b = g3 + ((size_t)b * 64 * N_ + n) * 2;
  for (int c = 0; c < 64; c++) {
    float v = (1.f - f2) * g3b[c * (N_ * 2)] + f2 * g3b[c * (N_ * 2) + 1];
    a0 += v * W[(og) * 192 + 128 + c];
    a1 += v * W[(og + 16) * 192 + 128 + c];
    a2 += v * W[(og + 32) * 192 + 128 + c];
    a3 += v * W[(og + 48) * 192 + 128 + c];
  }
  float accs[4] = {a0, a1, a2, a3};
#pragma unroll
  for (int k = 0; k < 4; k++) {
    int o = og + 16 * k;
    float y = accs[k] + bias[o];
    float s1 = pg[o] / sqrtf(pv[o] + 1e-5f);
    float fv = (y - pm[o]) * s1 + pb[o];
    size_t off = ((size_t)b * 64 + o) * NT + pos;
    fus[off] = fv;
    float xr = x[off];
    float s2 = bg[o] / sqrtf(bv2[o] + 1e-5f);
    x[off] = (fv + xr - bm2[o]) * s2 + bb2[o];
  }
}

// ---------------- k5e: skip conv at t=T-1 only ----------------
__global__ __launch_bounds__(256) void k5e_skip(const float* __restrict__ fus,
                                                const float* __restrict__ W,
                                                const float* __restrict__ bias,
                                                float* __restrict__ skip, int accum) {
  int idx = blockIdx.x * 256 + threadIdx.x;
  if (idx >= B_ * 128 * N_) return;
  int n = idx % N_, s = (idx / N_) & 127, b = idx / (N_ * 128);
  const float* fb = fus + (size_t)b * 64 * NT + n * 12 + 11;
  float a = bias[s];
  for (int c = 0; c < 64; c++) a += fb[(size_t)c * NT] * W[s * 64 + c];
  size_t o = ((size_t)b * 128 + s) * N_ + n;
  skip[o] = accum ? (skip[o] + a) : a;
}

// ---------------- k6: end MLP per (b,n) — fp32 output ----------------
__global__ __launch_bounds__(256) void k6_end(const float* __restrict__ skip,
                                              const float* __restrict__ w1,
                                              const float* __restrict__ b1,
                                              const float* __restrict__ w2,
                                              const float* __restrict__ b2,
                                              float* __restrict__ out) {
  __shared__ float sk[128];
  __shared__ float h[256];
  const int blk = blockIdx.x;
  const int b = blk / N_;
  const int n = blk - N_ * b;
  const int tid = threadIdx.x;
  if (tid < 128) sk[tid] = fmaxf(skip[((size_t)b * 128 + tid) * N_ + n], 0.f);
  __syncthreads();
  {
    float a = b1[tid];
    for (int s = 0; s < 128; s++) a += w1[tid * 128 + s] * sk[s];
    h[tid] = fmaxf(a, 0.f);
  }
  __syncthreads();
  if (tid < 12) {
    float a = b2[tid];
    for (int e = 0; e < 256; e++) a += w2[tid * 256 + e] * h[e];
    out[((size_t)b * 12 + tid) * N_ + n] = a;
  }
}

// ---------------- host ----------------
extern "C" void kernel_launch(void* const* d_in, const int* in_sizes, int n_in,
                              void* d_out, int out_size, void* d_ws, size_t ws_size,
                              hipStream_t stream) {
  (void)in_sizes; (void)n_in;
  if (ws_size < (size_t)44 * 1024 * 1024) {
    k_sentinel<<<(out_size + 255) / 256, 256, 0, stream>>>((float*)d_out, out_size);
    return;
  }
  const float* src = (const float*)d_in[0];
  const int* TE = (const int*)d_in[1];
  const float* sp = (const float*)d_in[2];
  const float* tp = (const float*)d_in[3];
  const float* SE = (const float*)d_in[4];
  const float* tmlp1_w = (const float*)d_in[5];
  const float* tmlp1_b = (const float*)d_in[6];
  const float* tmlp2_w = (const float*)d_in[7];
  const float* tmlp2_b = (const float*)d_in[8];
  const float* smlp1_w = (const float*)d_in[9];
  const float* smlp1_b = (const float*)d_in[10];
  const float* smlp2_w = (const float*)d_in[11];
  const float* smlp2_b = (const float*)d_in[12];
  const float* start_w = (const float*)d_in[13];
  const float* start_b = (const float*)d_in[14];
  const float* th1w = (const float*)d_in[15];
  const float* th1b = (const float*)d_in[16];
  const float* th2w = (const float*)d_in[17];
  const float* th2b = (const float*)d_in[18];
  const float* stw = (const float*)d_in[19];
  const float* stb = (const float*)d_in[20];
  const float* stg = (const float*)d_in[21];
  const float* stbb = (const float*)d_in[22];
  const float* stm = (const float*)d_in[23];
  const float* stv = (const float*)d_in[24];
  const float* p1w = (const float*)d_in[25];
  const float* p1b = (const float*)d_in[26];
  const float* p2w = (const float*)d_in[27];
  const float* p2b = (const float*)d_in[28];
  const float* p3w = (const float*)d_in[29];
  const float* p3b = (const float*)d_in[30];
  const float* pcw = (const float*)d_in[31];
  const float* pcb = (const float*)d_in[32];
  const float* pbg = (const float*)d_in[33];
  const float* pbb = (const float*)d_in[34];
  const float* pbm = (const float*)d_in[35];
  const float* pbv = (const float*)d_in[36];
  const float* skw = (const float*)d_in[37];
  const float* skb = (const float*)d_in[38];
  const float* bng = (const float*)d_in[39];
  const float* bnb = (const float*)d_in[40];
  const float* bnm = (const float*)d_in[41];
  const float* bnv = (const float*)d_in[42];
  const float* e1w = (const float*)d_in[43];
  const float* e1b = (const float*)d_in[44];
  const float* e2w = (const float*)d_in[45];
  const float* e2b = (const float*)d_in[46];

  float* ws = (float*)d_ws;
  float* coef = ws + 0;              // 2*8*66
  float* LsT  = ws + 8192;           // 325*328
  float* gA   = ws + 131072;         // 512*3900 (k3 scratch; aliased by fus)
  float* gB   = ws + 2162688;        // 512*3900 (k3 scratch; aliased by g2/g3)
  float* fus  = gA;
  float* g2   = gB;
  float* g3   = gB + 1048576;
  float* x    = ws + 4194304;        // [B,64,N,T]
  float* xst  = ws + 6291456;        // x_st; reused as g1
  float* hid  = ws + 8388608;        // hidden
  float* skipb= ws + 10485760;       // [B,128,N]

  k0_convert<<<(N_ * LSP + 255) / 256, 256, 0, stream>>>(sp, LsT);
  k1_embed<<<1, 256, 0, stream>>>(TE, SE, tmlp1_w, tmlp1_b, tmlp2_w, tmlp2_b,
                                  smlp1_w, smlp1_b, smlp2_w, smlp2_b,
                                  th1w, th1b, th2w, th2b, coef);
  k2_start<<<(B_ * C_ * NT + 255) / 256, 256, 0, stream>>>(src, start_w, start_b, x);

  for (int l = 0; l < 2; l++) {
    k3_basis<<<512, 256, 0, stream>>>(x, LsT, tp, coef + l * 528, xst, gA, gB);
    k4_stmlp<<<(B_ * 16 * NT + 255) / 256, 256, 0, stream>>>(
        x, xst, stw + l * 8192, stb + l * 64, stg + l * 64, stbb + l * 64,
        stm + l * 64, stv + l * 64, hid);
    k5a_pyr1<<<(B_ * 32 * NT + 255) / 256, 256, 0, stream>>>(
        hid, p1w + l * 8192, p1b + l * 128, xst /* g1 */);
    k5b_pyr2<<<(B_ * 32 * N_ * 4 + 255) / 256, 256, 0, stream>>>(
        hid, p2w + l * 24576, p2b + l * 128, g2);
    k5c_pyr3<<<(B_ * 32 * N_ * 2 + 255) / 256, 256, 0, stream>>>(
        hid, p3w + l * 49152, p3b + l * 128, g3);
    k5d_fuse<<<(B_ * 16 * NT + 255) / 256, 256, 0, stream>>>(
        xst /* g1 */, g2, g3, pcw + l * 12288, pcb + l * 64,
        pbg + l * 64, pbb + l * 64, pbm + l * 64, pbv + l * 64,
        bng + l * 64, bnb + l * 64, bnm + l * 64, bnv + l * 64, fus, x);
    k5e_skip<<<(B_ * 128 * N_ + 255) / 256, 256, 0, stream>>>(
        fus, skw + l * 8192, skb + l * 128, skipb, l);
  }
  k6_end<<<B_ * N_, 256, 0, stream>>>(skipb, e1w, e1b, e2w, e2b, (float*)d_out);
}

// Round 6
// 2230.377 us; speedup vs baseline: 1.4181x; 1.4181x over previous
//
#include <hip/hip_runtime.h>
#include <hip/hip_bf16.h>
#include <math.h>

// ---------------- problem constants ----------------
#define B_   8
#define T_   12
#define N_   325
#define C_   64
#define NT   3900     // N_*T_
#define LSP  328      // padded row stride of transposed sp matrix

__device__ __forceinline__ float sigm(float x) { return 1.f / (1.f + expf(-x)); }

// legacy 256-thread block reduction (k1/k6 helpers do not use it; kept for clarity)
__device__ __forceinline__ float blk_sum(float v, float* red) {
#pragma unroll
  for (int off = 1; off < 64; off <<= 1) v += __shfl_xor(v, off, 64);
  const int tid = threadIdx.x;
  __syncthreads();
  if ((tid & 63) == 0) red[tid >> 6] = v;
  __syncthreads();
  return red[0] + red[1] + red[2] + red[3];
}

// 512-thread (8-wave) multi-value reduction; ONE barrier (caller ping-pongs redb)
__device__ __forceinline__ void redN(float* v, int nv, float (*redb)[4], int tid) {
#pragma unroll
  for (int off = 1; off < 64; off <<= 1) {
    for (int i = 0; i < nv; i++) v[i] += __shfl_xor(v[i], off, 64);
  }
  if ((tid & 63) == 0) {
    for (int i = 0; i < nv; i++) redb[tid >> 6][i] = v[i];
  }
  __syncthreads();
  for (int i = 0; i < nv; i++) {
    float s = 0.f;
#pragma unroll
    for (int w = 0; w < 8; w++) s += redb[w][i];
    v[i] = s;
  }
}

// ---------------- sentinel (ws too small diagnostic) ----------------
__global__ __launch_bounds__(256) void k_sentinel(float* out, int n) {
  int i = blockIdx.x * 256 + threadIdx.x;
  if (i < n) out[i] = 7.0f;
}

// ---------------- k0: transpose sp (padded) ----------------
__global__ __launch_bounds__(256) void k0_convert(const float* __restrict__ sp,
                                                  float* __restrict__ LsT) {
  int idx = blockIdx.x * 256 + threadIdx.x;
  if (idx < N_ * LSP) {
    int m = idx / LSP, n = idx - m * LSP;
    LsT[idx] = (n < N_) ? sp[n * N_ + m] : 0.f;   // LsT[m][n] = Ls[n][m]
  }
}

// ---------------- k1: embeddings + theta coefficients ----------------
__global__ __launch_bounds__(256) void k1_embed(
    const int* __restrict__ TE, const float* __restrict__ SE,
    const float* __restrict__ w1, const float* __restrict__ b1,
    const float* __restrict__ w2, const float* __restrict__ b2,
    const float* __restrict__ sw1, const float* __restrict__ sb1,
    const float* __restrict__ sw2, const float* __restrict__ sb2,
    const float* __restrict__ t1w, const float* __restrict__ t1b,
    const float* __restrict__ t2w, const float* __restrict__ t2b,
    float* __restrict__ coef) {
  __shared__ float te2[8][10][12];
  __shared__ float ste[8][5][10];
  __shared__ float se1[5][10];
  __shared__ float se2[5][10];
  __shared__ float th[8][6][10];
  __shared__ int te64;
  const int tid = threadIdx.x;
  if (tid == 0) {
    int nz = 0;
    for (int k2 = 0; k2 < 96; k2++) nz += (TE[2 * k2 + 1] != 0) ? 1 : 0;
    te64 = (nz == 0) ? 1 : 0;
  }
  __syncthreads();
  for (int idx = tid; idx < 960; idx += 256) {
    int t = idx % 12, o = (idx / 12) % 10, b = idx / 120;
    int q = (b * 12 + t) * 2;
    int d = (te64 ? TE[2 * q] : TE[q]) % 7;
    int h = (te64 ? TE[2 * q + 2] : TE[q + 1]) % 288;
    float v = w1[o * 295 + d] + w1[o * 295 + 7 + h] + b1[o];
    te2[b][o][t] = fmaxf(v, 0.f);
  }
  __syncthreads();
  for (int idx = tid; idx < 400; idx += 256) {
    int s = idx % 10, o = (idx / 10) % 5, b = idx / 50;
    float a = b2[o];
    for (int t = 0; t < 12; t++) a += te2[b][s][t] * w2[o * 12 + t];
    ste[b][o][s] = fmaxf(a, 0.f);
  }
  if (tid < 50) {
    int o = tid / 10, j = tid % 10;
    float a = sb1[o];
    for (int n = 0; n < N_; n++) a += sw1[o * N_ + n] * SE[n * 10 + j];
    se1[o][j] = fmaxf(a, 0.f);
  }
  __syncthreads();
  if (tid < 50) {
    int t = tid / 10, s = tid % 10;
    float a = sb2[s];
    for (int j = 0; j < 10; j++) a += sw2[s * 10 + j] * se1[t][j];
    se2[t][s] = fmaxf(a, 0.f);
  }
  __syncthreads();
  for (int idx = tid; idx < 400; idx += 256) {
    int s = idx % 10, o = (idx / 10) % 5, b = idx / 50;
    ste[b][o][s] = fmaxf(se2[o][s] + ste[b][o][s], 0.f);
  }
  __syncthreads();
  for (int l = 0; l < 2; l++) {
    for (int idx = tid; idx < 480; idx += 256) {
      int s = idx % 10, q = (idx / 10) % 6, b = idx / 60;
      float a = t1b[l * 6 + q];
      for (int t = 0; t < 5; t++) a += ste[b][t][s] * t1w[(l * 6 + q) * 5 + t];
      th[b][q][s] = a;
    }
    __syncthreads();
    for (int idx = tid; idx < 528; idx += 256) {
      int q = idx % 6, p = (idx / 6) % 11, b = idx / 66;
      float a = t2b[l * 11 + p];
      for (int s = 0; s < 10; s++) a += th[b][q][s] * t2w[(l * 11 + p) * 10 + s];
      coef[(l * 8 + b) * 66 + q * 11 + p] = fmaxf(a, 0.f);
    }
    __syncthreads();
  }
}

// ---------------- k2: start 1x1 conv ----------------
__global__ __launch_bounds__(256) void k2_start(const float* __restrict__ src,
                                                const float* __restrict__ w,
                                                const float* __restrict__ bia,
                                                float* __restrict__ x) {
  int idx = blockIdx.x * 256 + threadIdx.x;
  if (idx >= B_ * C_ * NT) return;
  int pos = idx % NT, r = idx / NT, c = r & 63, b = r >> 6;
  int n = pos / 12, t = pos - 12 * n;
  float s = src[(b * 12 + t) * N_ + n];
  x[idx] = s * w[c] + bia[c];
}

// ---------------- k3: fused basis recursion + x_st accumulation ----------------
// 512 threads/block, one block per (b,c) slice. Thread tile = 2 rows x 4 cols
// (489 active units). Whole recursion state in LDS: 2 spatial ping-pong slots +
// 3 temporal rotation slots (5 x 15.6 KB = 78 KB -> 2 blocks/CU, 16 waves/CU).
// Reductions batched (A,B,C in one pass; d2 = B - d1*C) with ping-pong buffers.
__global__ __launch_bounds__(512, 4) void k3_basis(
    const float* __restrict__ x, const float* __restrict__ LsT,
    const float* __restrict__ tp, const float* __restrict__ coef,
    float* __restrict__ xst) {
  __shared__ float sb[5][3904];
  __shared__ float ltS[144];
  __shared__ float sred[2][8][4];
  const int tid = threadIdx.x;
  const int bc = blockIdx.x;
  const float* cf = coef + (bc >> 6) * 66;
  const float* xs = x + (size_t)bc * NT;
  float* xo = xst + (size_t)bc * NT;
  if (tid < 144) ltS[tid] = tp[tid];

  const int pr = tid / 3;            // row-pair index
  const int tb = tid - 3 * pr;       // t-quad index 0..2
  const int n0 = 2 * pr;
  const int t0 = 4 * tb;
  const bool act = (tid < 489);      // 163 row-pairs x 3 quads
  const bool r1 = act && (n0 + 1 < N_);
  const int e0 = n0 * 12 + t0;

  float acc0[4], acc1[4], rr0[4], rr1[4], l0[4], l1[4], s0[4], s1[4];
#pragma unroll
  for (int j = 0; j < 4; j++) { acc0[j] = 0.f; acc1[j] = 0.f; }

  int p = 0;      // reduction buffer ping-pong
  int m = 0;      // coefficient index
  int spc = 0;    // spatial "last" slot (0/1)

  // ---- m00 = unit(residual slice) ----
  {
#pragma unroll
    for (int j = 0; j < 4; j++) { rr0[j] = 0.f; rr1[j] = 0.f; }
    float np = 0.f;
    if (act) {
      const float4 q = *(const float4*)(xs + e0);
      rr0[0] = q.x; rr0[1] = q.y; rr0[2] = q.z; rr0[3] = q.w;
      if (r1) {
        const float4 q1 = *(const float4*)(xs + e0 + 12);
        rr1[0] = q1.x; rr1[1] = q1.y; rr1[2] = q1.z; rr1[3] = q1.w;
      }
#pragma unroll
      for (int j = 0; j < 4; j++) np += rr0[j] * rr0[j] + rr1[j] * rr1[j];
    }
    p ^= 1; redN(&np, 1, sred[p], tid);
    const float inv = 1.f / fmaxf(sqrtf(np), 1e-8f);
    const float c0 = cf[m]; m++;
    if (act) {
      float4 w;
#pragma unroll
      for (int j = 0; j < 4; j++) { rr0[j] *= inv; acc0[j] += c0 * rr0[j]; }
      w.x = rr0[0]; w.y = rr0[1]; w.z = rr0[2]; w.w = rr0[3];
      *(float4*)&sb[spc][e0] = w;
      if (r1) {
#pragma unroll
        for (int j = 0; j < 4; j++) { rr1[j] *= inv; acc1[j] += c0 * rr1[j]; }
        w.x = rr1[0]; w.y = rr1[1]; w.z = rr1[2]; w.w = rr1[3];
        *(float4*)&sb[spc][e0 + 12] = w;
      }
    }
    __syncthreads();
  }

  int lt = spc, sx = -1;   // temporal chain: last slot / sec slot (-1 = none)
  for (int i = 0; i <= 10; i++) {
    if (i > 0) {
      // ---------- spatial step: last = sb[spc], sec = sb[1-spc] ----------
      const int sps = 1 - spc;
      const bool hasSec = (i >= 2);
      float v3[3] = {0.f, 0.f, 0.f};
#pragma unroll
      for (int j = 0; j < 4; j++) {
        rr0[j] = 0.f; rr1[j] = 0.f; l0[j] = 0.f; l1[j] = 0.f;
        s0[j] = 0.f; s1[j] = 0.f;
      }
      if (act) {
        const float* lpc = LsT + n0;
        const float* sc = &sb[spc][t0];
#pragma unroll 4
        for (int mm = 0; mm < N_; mm++) {
          const float2 a = *(const float2*)(lpc + mm * LSP);  // pad col -> 0
          const float4 mr = *(const float4*)(sc + mm * 12);   // broadcast
          rr0[0] += a.x * mr.x; rr0[1] += a.x * mr.y;
          rr0[2] += a.x * mr.z; rr0[3] += a.x * mr.w;
          rr1[0] += a.y * mr.x; rr1[1] += a.y * mr.y;
          rr1[2] += a.y * mr.z; rr1[3] += a.y * mr.w;
        }
        {
          const float4 q = *(const float4*)&sb[spc][e0];
          l0[0] = q.x; l0[1] = q.y; l0[2] = q.z; l0[3] = q.w;
        }
        if (r1) {
          const float4 q = *(const float4*)&sb[spc][e0 + 12];
          l1[0] = q.x; l1[1] = q.y; l1[2] = q.z; l1[3] = q.w;
        }
#pragma unroll
        for (int j = 0; j < 4; j++) v3[0] += rr0[j] * l0[j] + rr1[j] * l1[j];
        if (hasSec) {
          {
            const float4 q = *(const float4*)&sb[sps][e0];
            s0[0] = q.x; s0[1] = q.y; s0[2] = q.z; s0[3] = q.w;
          }
          if (r1) {
            const float4 q = *(const float4*)&sb[sps][e0 + 12];
            s1[0] = q.x; s1[1] = q.y; s1[2] = q.z; s1[3] = q.w;
          }
#pragma unroll
          for (int j = 0; j < 4; j++) {
            v3[1] += rr0[j] * s0[j] + rr1[j] * s1[j];
            v3[2] += l0[j] * s0[j] + l1[j] * s1[j];
          }
        }
      }
      p ^= 1;
      if (hasSec) redN(v3, 3, sred[p], tid); else redN(v3, 1, sred[p], tid);
      const float d1 = v3[0];
      const float d2 = hasSec ? (v3[1] - d1 * v3[2]) : 0.f;
      float np = 0.f;
      if (act) {
#pragma unroll
        for (int j = 0; j < 4; j++) {
          rr0[j] -= d1 * l0[j] + d2 * s0[j];
          rr1[j] -= d1 * l1[j] + d2 * s1[j];
          np += rr0[j] * rr0[j] + rr1[j] * rr1[j];
        }
      }
      p ^= 1; redN(&np, 1, sred[p], tid);
      const float inv = 1.f / fmaxf(sqrtf(np), 1e-8f);
      const float c = cf[m]; m++;
      if (act) {   // overwrite old sec slot (all reads of it completed pre-bar)
        float4 w;
#pragma unroll
        for (int j = 0; j < 4; j++) { rr0[j] *= inv; acc0[j] += c * rr0[j]; }
        w.x = rr0[0]; w.y = rr0[1]; w.z = rr0[2]; w.w = rr0[3];
        *(float4*)&sb[sps][e0] = w;
        if (r1) {
#pragma unroll
          for (int j = 0; j < 4; j++) { rr1[j] *= inv; acc1[j] += c * rr1[j]; }
          w.x = rr1[0]; w.y = rr1[1]; w.z = rr1[2]; w.w = rr1[3];
          *(float4*)&sb[sps][e0 + 12] = w;
        }
      }
      spc = sps;
      lt = spc; sx = -1;
      __syncthreads();
    }
    // ---------- temporal chain (5 steps) ----------
    for (int j5 = 0; j5 < 5; j5++) {
      const int tg = (sx < 2) ? ((lt == 2) ? 3 : 2) : (9 - lt - sx);
      const bool hasSec = (sx >= 0);
      float v3[3] = {0.f, 0.f, 0.f};
#pragma unroll
      for (int j = 0; j < 4; j++) {
        rr0[j] = 0.f; rr1[j] = 0.f; l0[j] = 0.f; l1[j] = 0.f;
        s0[j] = 0.f; s1[j] = 0.f;
      }
      if (act) {
        float row0[12], row1[12];
        {
          const float4 a = *(const float4*)&sb[lt][n0 * 12];
          const float4 b4 = *(const float4*)&sb[lt][n0 * 12 + 4];
          const float4 c4 = *(const float4*)&sb[lt][n0 * 12 + 8];
          row0[0] = a.x; row0[1] = a.y; row0[2] = a.z; row0[3] = a.w;
          row0[4] = b4.x; row0[5] = b4.y; row0[6] = b4.z; row0[7] = b4.w;
          row0[8] = c4.x; row0[9] = c4.y; row0[10] = c4.z; row0[11] = c4.w;
        }
        if (r1) {
          const float4 a = *(const float4*)&sb[lt][n0 * 12 + 12];
          const float4 b4 = *(const float4*)&sb[lt][n0 * 12 + 16];
          const float4 c4 = *(const float4*)&sb[lt][n0 * 12 + 20];
          row1[0] = a.x; row1[1] = a.y; row1[2] = a.z; row1[3] = a.w;
          row1[4] = b4.x; row1[5] = b4.y; row1[6] = b4.z; row1[7] = b4.w;
          row1[8] = c4.x; row1[9] = c4.y; row1[10] = c4.z; row1[11] = c4.w;
        } else {
#pragma unroll
          for (int t = 0; t < 12; t++) row1[t] = 0.f;
        }
#pragma unroll
        for (int j = 0; j < 4; j++) {
          float a0 = 0.f, a1 = 0.f;
#pragma unroll
          for (int t = 0; t < 12; t++) {
            const float w = ltS[t * 12 + t0 + j];
            a0 += row0[t] * w; a1 += row1[t] * w;
          }
          rr0[j] = a0; rr1[j] = a1;
          l0[j] = row0[t0 + j]; l1[j] = row1[t0 + j];
        }
#pragma unroll
        for (int j = 0; j < 4; j++) v3[0] += rr0[j] * l0[j] + rr1[j] * l1[j];
        if (hasSec) {
          {
            const float4 q = *(const float4*)&sb[sx][e0];
            s0[0] = q.x; s0[1] = q.y; s0[2] = q.z; s0[3] = q.w;
          }
          if (r1) {
            const float4 q = *(const float4*)&sb[sx][e0 + 12];
            s1[0] = q.x; s1[1] = q.y; s1[2] = q.z; s1[3] = q.w;
          }
#pragma unroll
          for (int j = 0; j < 4; j++) {
            v3[1] += rr0[j] * s0[j] + rr1[j] * s1[j];
            v3[2] += l0[j] * s0[j] + l1[j] * s1[j];
          }
        }
      }
      p ^= 1;
      if (hasSec) redN(v3, 3, sred[p], tid); else redN(v3, 1, sred[p], tid);
      const float d1 = v3[0];
      const float d2 = hasSec ? (v3[1] - d1 * v3[2]) : 0.f;
      float np = 0.f;
      if (act) {
#pragma unroll
        for (int j = 0; j < 4; j++) {
          rr0[j] -= d1 * l0[j] + d2 * s0[j];
          rr1[j] -= d1 * l1[j] + d2 * s1[j];
          np += rr0[j] * rr0[j] + rr1[j] * rr1[j];
        }
      }
      p ^= 1; redN(&np, 1, sred[p], tid);
      const float inv = 1.f / fmaxf(sqrtf(np), 1e-8f);
      const float c = cf[m]; m++;
      if (act) {
        float4 w;
#pragma unroll
        for (int j = 0; j < 4; j++) { rr0[j] *= inv; acc0[j] += c * rr0[j]; }
        w.x = rr0[0]; w.y = rr0[1]; w.z = rr0[2]; w.w = rr0[3];
        *(float4*)&sb[tg][e0] = w;
        if (r1) {
#pragma unroll
          for (int j = 0; j < 4; j++) { rr1[j] *= inv; acc1[j] += c * rr1[j]; }
          w.x = rr1[0]; w.y = rr1[1]; w.z = rr1[2]; w.w = rr1[3];
          *(float4*)&sb[tg][e0 + 12] = w;
        }
      }
      sx = lt; lt = tg;
      __syncthreads();
    }
  }
  if (act) {
    float4 w;
    w.x = acc0[0]; w.y = acc0[1]; w.z = acc0[2]; w.w = acc0[3];
    *(float4*)(xo + e0) = w;
    if (r1) {
      w.x = acc1[0]; w.y = acc1[1]; w.z = acc1[2]; w.w = acc1[3];
      *(float4*)(xo + e0 + 12) = w;
    }
  }
}

// ---------------- k4: st_mlp + bn -> hidden ----------------
__global__ __launch_bounds__(256) void k4_stmlp(
    const float* __restrict__ x, const float* __restrict__ xst,
    const float* __restrict__ W, const float* __restrict__ bias,
    const float* __restrict__ g, const float* __restrict__ bb,
    const float* __restrict__ bm, const float* __restrict__ bv,
    float* __restrict__ hid) {
  int idx = blockIdx.x * 256 + threadIdx.x;
  if (idx >= B_ * 16 * NT) return;
  int pos = idx % NT, r = idx / NT, og = r & 15, b = r >> 4;
  const float* xb = x + (size_t)b * 64 * NT + pos;
  const float* xsb = xst + (size_t)b * 64 * NT + pos;
  float a0 = 0, a1 = 0, a2 = 0, a3 = 0;
  for (int i = 0; i < 64; i++) {
    float h = xb[(size_t)i * NT];
    a0 += h * W[(og) * 128 + i];
    a1 += h * W[(og + 16) * 128 + i];
    a2 += h * W[(og + 32) * 128 + i];
    a3 += h * W[(og + 48) * 128 + i];
  }
  for (int i = 0; i < 64; i++) {
    float h = xsb[(size_t)i * NT];
    a0 += h * W[(og) * 128 + 64 + i];
    a1 += h * W[(og + 16) * 128 + 64 + i];
    a2 += h * W[(og + 32) * 128 + 64 + i];
    a3 += h * W[(og + 48) * 128 + 64 + i];
  }
  float accs[4] = {a0, a1, a2, a3};
#pragma unroll
  for (int k = 0; k < 4; k++) {
    int o = og + 16 * k;
    float y = accs[k] + bias[o];
    float sc = g[o] / sqrtf(bv[o] + 1e-5f);
    hid[((size_t)b * 64 + o) * NT + pos] = (y - bm[o]) * sc + bb[o];
  }
}

// ---------------- k5a: pyr1 gated ----------------
__global__ __launch_bounds__(256) void k5a_pyr1(const float* __restrict__ hid,
                                                const float* __restrict__ W,
                                                const float* __restrict__ bias,
                                                float* __restrict__ g1) {
  int idx = blockIdx.x * 256 + threadIdx.x;
  if (idx >= B_ * 32 * NT) return;
  int pos = idx % NT, r = idx / NT, cg = r & 31, b = r >> 5;
  const float* hb = hid + (size_t)b * 64 * NT + pos;
  float s0 = 0, u0 = 0, s1 = 0, u1 = 0;
  for (int i = 0; i < 64; i++) {
    float h = hb[(size_t)i * NT];
    s0 += h * W[(cg) * 64 + i];
    u0 += h * W[(cg + 64) * 64 + i];
    s1 += h * W[(cg + 32) * 64 + i];
    u1 += h * W[(cg + 96) * 64 + i];
  }
  g1[((size_t)b * 64 + cg) * NT + pos] =
      sigm(s0 + bias[cg]) * tanhf(u0 + bias[cg + 64]);
  g1[((size_t)b * 64 + cg + 32) * NT + pos] =
      sigm(s1 + bias[cg + 32]) * tanhf(u1 + bias[cg + 96]);
}

// ---------------- k5b: pyr2 gated ----------------
__global__ __launch_bounds__(256) void k5b_pyr2(const float* __restrict__ hid,
                                                const float* __restrict__ W,
                                                const float* __restrict__ bias,
                                                float* __restrict__ g2) {
  int idx = blockIdx.x * 256 + threadIdx.x;
  if (idx >= B_ * 32 * N_ * 4) return;
  int q = idx & 3, r = idx >> 2;
  int n = r % N_; r /= N_;
  int cg = r & 31, b = r >> 5;
  const float* hb = hid + (size_t)b * 64 * NT + n * 12 + 3 * q;
  float s0 = 0, u0 = 0, s1 = 0, u1 = 0;
  for (int i = 0; i < 64; i++) {
    const float* hh = hb + (size_t)i * NT;
#pragma unroll
    for (int k = 0; k < 3; k++) {
      float h = hh[k];
      s0 += h * W[(cg) * 192 + i * 3 + k];
      u0 += h * W[(cg + 64) * 192 + i * 3 + k];
      s1 += h * W[(cg + 32) * 192 + i * 3 + k];
      u1 += h * W[(cg + 96) * 192 + i * 3 + k];
    }
  }
  g2[(((size_t)b * 64 + cg) * N_ + n) * 4 + q] =
      sigm(s0 + bias[cg]) * tanhf(u0 + bias[cg + 64]);
  g2[(((size_t)b * 64 + cg + 32) * N_ + n) * 4 + q] =
      sigm(s1 + bias[cg + 32]) * tanhf(u1 + bias[cg + 96]);
}

// ---------------- k5c: pyr3 gated ----------------
__global__ __launch_bounds__(256) void k5c_pyr3(const float* __restrict__ hid,
                                                const float* __restrict__ W,
                                                const float* __restrict__ bias,
                                                float* __restrict__ g3) {
  int idx = blockIdx.x * 256 + threadIdx.x;
  if (idx >= B_ * 32 * N_ * 2) return;
  int q = idx & 1, r = idx >> 1;
  int n = r % N_; r /= N_;
  int cg = r & 31, b = r >> 5;
  const float* hb = hid + (size_t)b * 64 * NT + n * 12 + 6 * q;
  float s0 = 0, u0 = 0, s1 = 0, u1 = 0;
  for (int i = 0; i < 64; i++) {
    const float* hh = hb + (size_t)i * NT;
#pragma unroll
    for (int k = 0; k < 6; k++) {
      float h = hh[k];
      s0 += h * W[(cg) * 384 + i * 6 + k];
      u0 += h * W[(cg + 64) * 384 + i * 6 + k];
      s1 += h * W[(cg + 32) * 384 + i * 6 + k];
      u1 += h * W[(cg + 96) * 384 + i * 6 + k];
    }
  }
  g3[(((size_t)b * 64 + cg) * N_ + n) * 2 + q] =
      sigm(s0 + bias[cg]) * tanhf(u0 + bias[cg + 64]);
  g3[(((size_t)b * 64 + cg + 32) * N_ + n) * 2 + q] =
      sigm(s1 + bias[cg + 32]) * tanhf(u1 + bias[cg + 96]);
}

// ---------------- k5d: fusion conv + bn + residual bn ----------------
__global__ __launch_bounds__(256) void k5d_fuse(
    const float* __restrict__ g1, const float* __restrict__ g2, const float* __restrict__ g3,
    const float* __restrict__ W, const float* __restrict__ bias,
    const float* __restrict__ pg, const float* __restrict__ pb,
    const float* __restrict__ pm, const float* __restrict__ pv,
    const float* __restrict__ bg, const float* __restrict__ bb2,
    const float* __restrict__ bm2, const float* __restrict__ bv2,
    float* __restrict__ fus, float* __restrict__ x) {
  int idx = blockIdx.x * 256 + threadIdx.x;
  if (idx >= B_ * 16 * NT) return;
  int pos = idx % NT, r = idx / NT, og = r & 15, b = r >> 4;
  int n = pos / 12, t = pos - 12 * n;
  float a0 = 0, a1 = 0, a2 = 0, a3 = 0;
  const float* g1b = g1 + (size_t)b * 64 * NT + pos;
  for (int c = 0; c < 64; c++) {
    float v = g1b[(size_t)c * NT];
    a0 += v * W[(og) * 192 + c];
    a1 += v * W[(og + 16) * 192 + c];
    a2 += v * W[(og + 32) * 192 + c];
    a3 += v * W[(og + 48) * 192 + c];
  }
  float c4 = fminf(fmaxf((t - 1) * (1.f / 3.f), 0.f), 3.f);
  int q0 = (int)c4;
  float f4 = c4 - (float)q0;
  int q1 = min(q0 + 1, 3);
  const float* g2b = g2 + ((size_t)b * 64 * N_ + n) * 4;
  for (int c = 0; c < 64; c++) {
    float v = (1.f - f4) * g2b[c * (N_ * 4) + q0] + f4 * g2b[c * (N_ * 4) + q1];
    a0 += v * W[(og) * 192 + 64 + c];
    a1 += v * W[(og + 16) * 192 + 64 + c];
    a2 += v * W[(og + 32) * 192 + 64 + c];
    a3 += v * W[(og + 48) * 192 + 64 + c];
  }
  float f2 = fminf(fmaxf((2 * t - 5) * (1.f / 12.f), 0.f), 1.f);
  const float* g3b = g3 + ((size_t)b * 64 * N_ + n) * 2;
  for (int c = 0; c < 64; c++) {
    float v = (1.f - f2) * g3b[c * (N_ * 2)] + f2 * g3b[c * (N_ * 2) + 1];
    a0 += v * W[(og) * 192 + 128 + c];
    a1 += v * W[(og + 16) * 192 + 128 + c];
    a2 += v * W[(og + 32) * 192 + 128 + c];
    a3 += v * W[(og + 48) * 192 + 128 + c];
  }
  float accs[4] = {a0, a1, a2, a3};
#pragma unroll
  for (int k = 0; k < 4; k++) {
    int o = og + 16 * k;
    float y = accs[k] + bias[o];
    float s1 = pg[o] / sqrtf(pv[o] + 1e-5f);
    float fv = (y - pm[o]) * s1 + pb[o];
    size_t off = ((size_t)b * 64 + o) * NT + pos;
    fus[off] = fv;
    float xr = x[off];
    float s2 = bg[o] / sqrtf(bv2[o] + 1e-5f);
    x[off] = (fv + xr - bm2[o]) * s2 + bb2[o];
  }
}

// ---------------- k5e: skip conv at t=T-1 only ----------------
__global__ __launch_bounds__(256) void k5e_skip(const float* __restrict__ fus,
                                                const float* __restrict__ W,
                                                const float* __restrict__ bias,
                                                float* __restrict__ skip, int accum) {
  int idx = blockIdx.x * 256 + threadIdx.x;
  if (idx >= B_ * 128 * N_) return;
  int n = idx % N_, s = (idx / N_) & 127, b = idx / (N_ * 128);
  const float* fb = fus + (size_t)b * 64 * NT + n * 12 + 11;
  float a = bias[s];
  for (int c = 0; c < 64; c++) a += fb[(size_t)c * NT] * W[s * 64 + c];
  size_t o = ((size_t)b * 128 + s) * N_ + n;
  skip[o] = accum ? (skip[o] + a) : a;
}

// ---------------- k6: end MLP per (b,n) — fp32 output ----------------
__global__ __launch_bounds__(256) void k6_end(const float* __restrict__ skip,
                                              const float* __restrict__ w1,
                                              const float* __restrict__ b1,
                                              const float* __restrict__ w2,
                                              const float* __restrict__ b2,
                                              float* __restrict__ out) {
  __shared__ float sk[128];
  __shared__ float h[256];
  const int blk = blockIdx.x;
  const int b = blk / N_;
  const int n = blk - N_ * b;
  const int tid = threadIdx.x;
  if (tid < 128) sk[tid] = fmaxf(skip[((size_t)b * 128 + tid) * N_ + n], 0.f);
  __syncthreads();
  {
    float a = b1[tid];
    for (int s = 0; s < 128; s++) a += w1[tid * 128 + s] * sk[s];
    h[tid] = fmaxf(a, 0.f);
  }
  __syncthreads();
  if (tid < 12) {
    float a = b2[tid];
    for (int e = 0; e < 256; e++) a += w2[tid * 256 + e] * h[e];
    out[((size_t)b * 12 + tid) * N_ + n] = a;
  }
}

// ---------------- host ----------------
extern "C" void kernel_launch(void* const* d_in, const int* in_sizes, int n_in,
                              void* d_out, int out_size, void* d_ws, size_t ws_size,
                              hipStream_t stream) {
  (void)in_sizes; (void)n_in;
  if (ws_size < (size_t)44 * 1024 * 1024) {
    k_sentinel<<<(out_size + 255) / 256, 256, 0, stream>>>((float*)d_out, out_size);
    return;
  }
  const float* src = (const float*)d_in[0];
  const int* TE = (const int*)d_in[1];
  const float* sp = (const float*)d_in[2];
  const float* tp = (const float*)d_in[3];
  const float* SE = (const float*)d_in[4];
  const float* tmlp1_w = (const float*)d_in[5];
  const float* tmlp1_b = (const float*)d_in[6];
  const float* tmlp2_w = (const float*)d_in[7];
  const float* tmlp2_b = (const float*)d_in[8];
  const float* smlp1_w = (const float*)d_in[9];
  const float* smlp1_b = (const float*)d_in[10];
  const float* smlp2_w = (const float*)d_in[11];
  const float* smlp2_b = (const float*)d_in[12];
  const float* start_w = (const float*)d_in[13];
  const float* start_b = (const float*)d_in[14];
  const float* th1w = (const float*)d_in[15];
  const float* th1b = (const float*)d_in[16];
  const float* th2w = (const float*)d_in[17];
  const float* th2b = (const float*)d_in[18];
  const float* stw = (const float*)d_in[19];
  const float* stb = (const float*)d_in[20];
  const float* stg = (const float*)d_in[21];
  const float* stbb = (const float*)d_in[22];
  const float* stm = (const float*)d_in[23];
  const float* stv = (const float*)d_in[24];
  const float* p1w = (const float*)d_in[25];
  const float* p1b = (const float*)d_in[26];
  const float* p2w = (const float*)d_in[27];
  const float* p2b = (const float*)d_in[28];
  const float* p3w = (const float*)d_in[29];
  const float* p3b = (const float*)d_in[30];
  const float* pcw = (const float*)d_in[31];
  const float* pcb = (const float*)d_in[32];
  const float* pbg = (const float*)d_in[33];
  const float* pbb = (const float*)d_in[34];
  const float* pbm = (const float*)d_in[35];
  const float* pbv = (const float*)d_in[36];
  const float* skw = (const float*)d_in[37];
  const float* skb = (const float*)d_in[38];
  const float* bng = (const float*)d_in[39];
  const float* bnb = (const float*)d_in[40];
  const float* bnm = (const float*)d_in[41];
  const float* bnv = (const float*)d_in[42];
  const float* e1w = (const float*)d_in[43];
  const float* e1b = (const float*)d_in[44];
  const float* e2w = (const float*)d_in[45];
  const float* e2b = (const float*)d_in[46];

  float* ws = (float*)d_ws;
  float* coef = ws + 0;              // 2*8*66
  float* LsT  = ws + 8192;           // 325*328
  float* gA   = ws + 131072;         // (k3 no longer uses; aliased by fus)
  float* gB   = ws + 2162688;        // (aliased by g2/g3)
  float* fus  = gA;
  float* g2   = gB;
  float* g3   = gB + 1048576;
  float* x    = ws + 4194304;        // [B,64,N,T]
  float* xst  = ws + 6291456;        // x_st; reused as g1
  float* hid  = ws + 8388608;        // hidden
  float* skipb= ws + 10485760;       // [B,128,N]

  k0_convert<<<(N_ * LSP + 255) / 256, 256, 0, stream>>>(sp, LsT);
  k1_embed<<<1, 256, 0, stream>>>(TE, SE, tmlp1_w, tmlp1_b, tmlp2_w, tmlp2_b,
                                  smlp1_w, smlp1_b, smlp2_w, smlp2_b,
                                  th1w, th1b, th2w, th2b, coef);
  k2_start<<<(B_ * C_ * NT + 255) / 256, 256, 0, stream>>>(src, start_w, start_b, x);

  for (int l = 0; l < 2; l++) {
    k3_basis<<<512, 512, 0, stream>>>(x, LsT, tp, coef + l * 528, xst);
    k4_stmlp<<<(B_ * 16 * NT + 255) / 256, 256, 0, stream>>>(
        x, xst, stw + l * 8192, stb + l * 64, stg + l * 64, stbb + l * 64,
        stm + l * 64, stv + l * 64, hid);
    k5a_pyr1<<<(B_ * 32 * NT + 255) / 256, 256, 0, stream>>>(
        hid, p1w + l * 8192, p1b + l * 128, xst /* g1 */);
    k5b_pyr2<<<(B_ * 32 * N_ * 4 + 255) / 256, 256, 0, stream>>>(
        hid, p2w + l * 24576, p2b + l * 128, g2);
    k5c_pyr3<<<(B_ * 32 * N_ * 2 + 255) / 256, 256, 0, stream>>>(
        hid, p3w + l * 49152, p3b + l * 128, g3);
    k5d_fuse<<<(B_ * 16 * NT + 255) / 256, 256, 0, stream>>>(
        xst /* g1 */, g2, g3, pcw + l * 12288, pcb + l * 64,
        pbg + l * 64, pbb + l * 64, pbm + l * 64, pbv + l * 64,
        bng + l * 64, bnb + l * 64, bnm + l * 64, bnv + l * 64, fus, x);
    k5e_skip<<<(B_ * 128 * N_ + 255) / 256, 256, 0, stream>>>(
        fus, skw + l * 8192, skb + l * 128, skipb, l);
  }
  k6_end<<<B_ * N_, 256, 0, stream>>>(skipb, e1w, e1b, e2w, e2b, (float*)d_out);
}

// Round 7
// 1803.356 us; speedup vs baseline: 1.7540x; 1.2368x over previous
//
#include <hip/hip_runtime.h>
#include <hip/hip_bf16.h>
#include <math.h>

// ---------------- problem constants ----------------
#define B_   8
#define T_   12
#define N_   325
#define C_   64
#define NT   3900     // N_*T_
#define LSP  328      // padded row stride of transposed sp matrix

__device__ __forceinline__ float sigm(float x) { return 1.f / (1.f + expf(-x)); }

// 512-thread (8-wave) multi-value reduction; ONE barrier (caller ping-pongs redb)
__device__ __forceinline__ void redN(float* v, int nv, float (*redb)[4], int tid) {
#pragma unroll
  for (int off = 1; off < 64; off <<= 1) {
    for (int i = 0; i < nv; i++) v[i] += __shfl_xor(v[i], off, 64);
  }
  if ((tid & 63) == 0) {
    for (int i = 0; i < nv; i++) redb[tid >> 6][i] = v[i];
  }
  __syncthreads();
  for (int i = 0; i < nv; i++) {
    float s = 0.f;
#pragma unroll
    for (int w = 0; w < 8; w++) s += redb[w][i];
    v[i] = s;
  }
}

// ---------------- sentinel (ws too small diagnostic) ----------------
__global__ __launch_bounds__(256) void k_sentinel(float* out, int n) {
  int i = blockIdx.x * 256 + threadIdx.x;
  if (i < n) out[i] = 7.0f;
}

// ---------------- k0: transpose sp (padded) ----------------
__global__ __launch_bounds__(256) void k0_convert(const float* __restrict__ sp,
                                                  float* __restrict__ LsT) {
  int idx = blockIdx.x * 256 + threadIdx.x;
  if (idx < N_ * LSP) {
    int m = idx / LSP, n = idx - m * LSP;
    LsT[idx] = (n < N_) ? sp[n * N_ + m] : 0.f;   // LsT[m][n] = Ls[n][m]
  }
}

// ---------------- k1: embeddings + theta coefficients ----------------
__global__ __launch_bounds__(256) void k1_embed(
    const int* __restrict__ TE, const float* __restrict__ SE,
    const float* __restrict__ w1, const float* __restrict__ b1,
    const float* __restrict__ w2, const float* __restrict__ b2,
    const float* __restrict__ sw1, const float* __restrict__ sb1,
    const float* __restrict__ sw2, const float* __restrict__ sb2,
    const float* __restrict__ t1w, const float* __restrict__ t1b,
    const float* __restrict__ t2w, const float* __restrict__ t2b,
    float* __restrict__ coef) {
  __shared__ float te2[8][10][12];
  __shared__ float ste[8][5][10];
  __shared__ float se1[5][10];
  __shared__ float se2[5][10];
  __shared__ float th[8][6][10];
  __shared__ int te64;
  const int tid = threadIdx.x;
  if (tid == 0) {
    int nz = 0;
    for (int k2 = 0; k2 < 96; k2++) nz += (TE[2 * k2 + 1] != 0) ? 1 : 0;
    te64 = (nz == 0) ? 1 : 0;
  }
  __syncthreads();
  for (int idx = tid; idx < 960; idx += 256) {
    int t = idx % 12, o = (idx / 12) % 10, b = idx / 120;
    int q = (b * 12 + t) * 2;
    int d = (te64 ? TE[2 * q] : TE[q]) % 7;
    int h = (te64 ? TE[2 * q + 2] : TE[q + 1]) % 288;
    float v = w1[o * 295 + d] + w1[o * 295 + 7 + h] + b1[o];
    te2[b][o][t] = fmaxf(v, 0.f);
  }
  __syncthreads();
  for (int idx = tid; idx < 400; idx += 256) {
    int s = idx % 10, o = (idx / 10) % 5, b = idx / 50;
    float a = b2[o];
    for (int t = 0; t < 12; t++) a += te2[b][s][t] * w2[o * 12 + t];
    ste[b][o][s] = fmaxf(a, 0.f);
  }
  if (tid < 50) {
    int o = tid / 10, j = tid % 10;
    float a = sb1[o];
    for (int n = 0; n < N_; n++) a += sw1[o * N_ + n] * SE[n * 10 + j];
    se1[o][j] = fmaxf(a, 0.f);
  }
  __syncthreads();
  if (tid < 50) {
    int t = tid / 10, s = tid % 10;
    float a = sb2[s];
    for (int j = 0; j < 10; j++) a += sw2[s * 10 + j] * se1[t][j];
    se2[t][s] = fmaxf(a, 0.f);
  }
  __syncthreads();
  for (int idx = tid; idx < 400; idx += 256) {
    int s = idx % 10, o = (idx / 10) % 5, b = idx / 50;
    ste[b][o][s] = fmaxf(se2[o][s] + ste[b][o][s], 0.f);
  }
  __syncthreads();
  for (int l = 0; l < 2; l++) {
    for (int idx = tid; idx < 480; idx += 256) {
      int s = idx % 10, q = (idx / 10) % 6, b = idx / 60;
      float a = t1b[l * 6 + q];
      for (int t = 0; t < 5; t++) a += ste[b][t][s] * t1w[(l * 6 + q) * 5 + t];
      th[b][q][s] = a;
    }
    __syncthreads();
    for (int idx = tid; idx < 528; idx += 256) {
      int q = idx % 6, p = (idx / 6) % 11, b = idx / 66;
      float a = t2b[l * 11 + p];
      for (int s = 0; s < 10; s++) a += th[b][q][s] * t2w[(l * 11 + p) * 10 + s];
      coef[(l * 8 + b) * 66 + q * 11 + p] = fmaxf(a, 0.f);
    }
    __syncthreads();
  }
}

// ---------------- k2: start 1x1 conv ----------------
__global__ __launch_bounds__(256) void k2_start(const float* __restrict__ src,
                                                const float* __restrict__ w,
                                                const float* __restrict__ bia,
                                                float* __restrict__ x) {
  int idx = blockIdx.x * 256 + threadIdx.x;
  if (idx >= B_ * C_ * NT) return;
  int pos = idx % NT, r = idx / NT, c = r & 63, b = r >> 6;
  int n = pos / 12, t = pos - 12 * n;
  float s = src[(b * 12 + t) * N_ + n];
  x[idx] = s * w[c] + bia[c];
}

// ---------------- k3: fused basis recursion + x_st accumulation ----------------
// 512 threads/block, one block per (b,c) slice.
// Spatial steps: 489-thread tiled matmul (2 rows x 4 cols) against LDS slice
// (2 ping-pong LDS slots hold the two most recent SPATIAL basis matrices).
// Temporal chain: row-local in REGISTERS (one slice-row of 12 per thread, 325
// active) -- tp_matrix is tridiagonal by construction, so matvec = 22 FMAs
// with 11 wave-uniform weights; only scalar reductions cross threads.
__global__ __launch_bounds__(512, 4) void k3_basis(
    const float* __restrict__ x, const float* __restrict__ LsT,
    const float* __restrict__ tp, const float* __restrict__ coef,
    float* __restrict__ xst) {
  __shared__ float sb[2][3904];
  __shared__ float sred[2][8][4];
  const int tid = threadIdx.x;
  const int bc = blockIdx.x;
  const float* cf = coef + (bc >> 6) * 66;
  const float* xs = x + (size_t)bc * NT;
  float* xo = xst + (size_t)bc * NT;

  // spatial tiling: row-pair x t-quad (489 active)
  const int pr = tid / 3, tb = tid - 3 * pr;
  const int n0 = 2 * pr, t0 = 4 * tb;
  const bool actS = (tid < 489);
  const bool r1 = actS && (n0 + 1 < N_);
  const int e0 = n0 * 12 + t0;

  // temporal layout: one row per thread (325 active)
  const bool actT = (tid < N_);
  const int rowOff = tid * 12;

  // tridiagonal temporal operator: w[k] = tp[k][k+1] (= tp[k+1][k]); uniform
  float w[11];
#pragma unroll
  for (int k = 0; k < 11; k++) w[k] = tp[k * 12 + k + 1];

  float last[12], sec[12], acc[12], rr[12];

  int p = 0, m = 0, spc = 0;

  // ---- m00 = unit(residual slice) (temporal layout) ----
  {
    float np = 0.f;
#pragma unroll
    for (int u = 0; u < 12; u++) rr[u] = 0.f;
    if (actT) {
      const float4 a = *(const float4*)(xs + rowOff);
      const float4 b4 = *(const float4*)(xs + rowOff + 4);
      const float4 c4 = *(const float4*)(xs + rowOff + 8);
      rr[0] = a.x; rr[1] = a.y; rr[2] = a.z; rr[3] = a.w;
      rr[4] = b4.x; rr[5] = b4.y; rr[6] = b4.z; rr[7] = b4.w;
      rr[8] = c4.x; rr[9] = c4.y; rr[10] = c4.z; rr[11] = c4.w;
#pragma unroll
      for (int u = 0; u < 12; u++) np += rr[u] * rr[u];
    }
    p ^= 1; redN(&np, 1, sred[p], tid);
    const float inv = 1.f / fmaxf(sqrtf(np), 1e-8f);
    const float c0 = cf[m]; m++;
#pragma unroll
    for (int u = 0; u < 12; u++) {
      last[u] = rr[u] * inv;
      acc[u] = c0 * last[u];
      sec[u] = 0.f;
    }
    if (actT) {
      float4 wv;
      wv.x = last[0]; wv.y = last[1]; wv.z = last[2]; wv.w = last[3];
      *(float4*)&sb[0][rowOff] = wv;
      wv.x = last[4]; wv.y = last[5]; wv.z = last[6]; wv.w = last[7];
      *(float4*)&sb[0][rowOff + 4] = wv;
      wv.x = last[8]; wv.y = last[9]; wv.z = last[10]; wv.w = last[11];
      *(float4*)&sb[0][rowOff + 8] = wv;
    }
    __syncthreads();
  }

  for (int i = 0; i <= 10; i++) {
    if (i > 0) {
      // ---------- spatial step (489-layout): last_s=sb[spc], sec_s=sb[sps] --
      const int sps = 1 - spc;
      const bool hasSec = (i >= 2);
      float v3[3] = {0.f, 0.f, 0.f};
      float rr0[4], rr1[4], l0[4], l1[4], s0[4], s1[4];
#pragma unroll
      for (int j = 0; j < 4; j++) {
        rr0[j] = 0.f; rr1[j] = 0.f; l0[j] = 0.f; l1[j] = 0.f;
        s0[j] = 0.f; s1[j] = 0.f;
      }
      if (actS) {
        const float* lpc = LsT + n0;
        const float* sc = &sb[spc][t0];
#pragma unroll 4
        for (int mm = 0; mm < N_; mm++) {
          const float2 a = *(const float2*)(lpc + mm * LSP);  // pad col -> 0
          const float4 mr = *(const float4*)(sc + mm * 12);
          rr0[0] += a.x * mr.x; rr0[1] += a.x * mr.y;
          rr0[2] += a.x * mr.z; rr0[3] += a.x * mr.w;
          rr1[0] += a.y * mr.x; rr1[1] += a.y * mr.y;
          rr1[2] += a.y * mr.z; rr1[3] += a.y * mr.w;
        }
        {
          const float4 q = *(const float4*)&sb[spc][e0];
          l0[0] = q.x; l0[1] = q.y; l0[2] = q.z; l0[3] = q.w;
        }
        if (r1) {
          const float4 q = *(const float4*)&sb[spc][e0 + 12];
          l1[0] = q.x; l1[1] = q.y; l1[2] = q.z; l1[3] = q.w;
        }
#pragma unroll
        for (int j = 0; j < 4; j++) v3[0] += rr0[j] * l0[j] + rr1[j] * l1[j];
        if (hasSec) {
          {
            const float4 q = *(const float4*)&sb[sps][e0];
            s0[0] = q.x; s0[1] = q.y; s0[2] = q.z; s0[3] = q.w;
          }
          if (r1) {
            const float4 q = *(const float4*)&sb[sps][e0 + 12];
            s1[0] = q.x; s1[1] = q.y; s1[2] = q.z; s1[3] = q.w;
          }
#pragma unroll
          for (int j = 0; j < 4; j++) {
            v3[1] += rr0[j] * s0[j] + rr1[j] * s1[j];
            v3[2] += l0[j] * s0[j] + l1[j] * s1[j];
          }
        }
      }
      p ^= 1;
      if (hasSec) redN(v3, 3, sred[p], tid); else redN(v3, 1, sred[p], tid);
      const float d1 = v3[0];
      const float d2 = hasSec ? (v3[1] - d1 * v3[2]) : 0.f;
      float np = 0.f;
      if (actS) {
#pragma unroll
        for (int j = 0; j < 4; j++) {
          rr0[j] -= d1 * l0[j] + d2 * s0[j];
          rr1[j] -= d1 * l1[j] + d2 * s1[j];
          np += rr0[j] * rr0[j] + rr1[j] * rr1[j];
        }
      }
      p ^= 1; redN(&np, 1, sred[p], tid);
      const float inv = 1.f / fmaxf(sqrtf(np), 1e-8f);
      const float cs = cf[m]; m++;
      if (actS) {
        float4 wv;
        wv.x = rr0[0] * inv; wv.y = rr0[1] * inv;
        wv.z = rr0[2] * inv; wv.w = rr0[3] * inv;
        *(float4*)&sb[sps][e0] = wv;
        if (r1) {
          wv.x = rr1[0] * inv; wv.y = rr1[1] * inv;
          wv.z = rr1[2] * inv; wv.w = rr1[3] * inv;
          *(float4*)&sb[sps][e0 + 12] = wv;
        }
      }
      spc = sps;
      __syncthreads();
      // temporal-layout init: load new M_i0 row; acc += c*row; sec <- 0
      if (actT) {
        const float4 a = *(const float4*)&sb[spc][rowOff];
        const float4 b4 = *(const float4*)&sb[spc][rowOff + 4];
        const float4 c4 = *(const float4*)&sb[spc][rowOff + 8];
        last[0] = a.x; last[1] = a.y; last[2] = a.z; last[3] = a.w;
        last[4] = b4.x; last[5] = b4.y; last[6] = b4.z; last[7] = b4.w;
        last[8] = c4.x; last[9] = c4.y; last[10] = c4.z; last[11] = c4.w;
#pragma unroll
        for (int u = 0; u < 12; u++) {
          acc[u] += cs * last[u];
          sec[u] = 0.f;
        }
      }
    }
    // ---------- temporal chain (5 steps), fully register-resident ----------
    for (int j5 = 0; j5 < 5; j5++) {
      float v3[3] = {0.f, 0.f, 0.f};
      if (actT) {
#pragma unroll
        for (int u = 0; u < 12; u++) {
          float r = 0.f;
          if (u > 0) r += last[u - 1] * w[u - 1];
          if (u < 11) r += last[u + 1] * w[u];
          rr[u] = r;
          v3[0] += r * last[u];
          v3[1] += r * sec[u];
          v3[2] += last[u] * sec[u];
        }
      }
      p ^= 1; redN(v3, 3, sred[p], tid);
      const float d1 = v3[0];
      const float d2 = v3[1] - d1 * v3[2];   // exact 0 when sec==0
      float np = 0.f;
      if (actT) {
#pragma unroll
        for (int u = 0; u < 12; u++) {
          rr[u] -= d1 * last[u] + d2 * sec[u];
          np += rr[u] * rr[u];
        }
      }
      p ^= 1; redN(&np, 1, sred[p], tid);
      const float inv = 1.f / fmaxf(sqrtf(np), 1e-8f);
      const float c = cf[m]; m++;
      if (actT) {
#pragma unroll
        for (int u = 0; u < 12; u++) {
          const float v = rr[u] * inv;
          sec[u] = last[u];
          last[u] = v;
          acc[u] += c * v;
        }
      }
    }
  }
  if (actT) {
    float4 wv;
    wv.x = acc[0]; wv.y = acc[1]; wv.z = acc[2]; wv.w = acc[3];
    *(float4*)(xo + rowOff) = wv;
    wv.x = acc[4]; wv.y = acc[5]; wv.z = acc[6]; wv.w = acc[7];
    *(float4*)(xo + rowOff + 4) = wv;
    wv.x = acc[8]; wv.y = acc[9]; wv.z = acc[10]; wv.w = acc[11];
    *(float4*)(xo + rowOff + 8) = wv;
  }
}

// ---------------- k4: st_mlp + bn -> hidden ----------------
__global__ __launch_bounds__(256) void k4_stmlp(
    const float* __restrict__ x, const float* __restrict__ xst,
    const float* __restrict__ W, const float* __restrict__ bias,
    const float* __restrict__ g, const float* __restrict__ bb,
    const float* __restrict__ bm, const float* __restrict__ bv,
    float* __restrict__ hid) {
  int idx = blockIdx.x * 256 + threadIdx.x;
  if (idx >= B_ * 16 * NT) return;
  int pos = idx % NT, r = idx / NT, og = r & 15, b = r >> 4;
  const float* xb = x + (size_t)b * 64 * NT + pos;
  const float* xsb = xst + (size_t)b * 64 * NT + pos;
  float a0 = 0, a1 = 0, a2 = 0, a3 = 0;
  for (int i = 0; i < 64; i++) {
    float h = xb[(size_t)i * NT];
    a0 += h * W[(og) * 128 + i];
    a1 += h * W[(og + 16) * 128 + i];
    a2 += h * W[(og + 32) * 128 + i];
    a3 += h * W[(og + 48) * 128 + i];
  }
  for (int i = 0; i < 64; i++) {
    float h = xsb[(size_t)i * NT];
    a0 += h * W[(og) * 128 + 64 + i];
    a1 += h * W[(og + 16) * 128 + 64 + i];
    a2 += h * W[(og + 32) * 128 + 64 + i];
    a3 += h * W[(og + 48) * 128 + 64 + i];
  }
  float accs[4] = {a0, a1, a2, a3};
#pragma unroll
  for (int k = 0; k < 4; k++) {
    int o = og + 16 * k;
    float y = accs[k] + bias[o];
    float sc = g[o] / sqrtf(bv[o] + 1e-5f);
    hid[((size_t)b * 64 + o) * NT + pos] = (y - bm[o]) * sc + bb[o];
  }
}

// ---------------- k5a: pyr1 gated ----------------
__global__ __launch_bounds__(256) void k5a_pyr1(const float* __restrict__ hid,
                                                const float* __restrict__ W,
                                                const float* __restrict__ bias,
                                                float* __restrict__ g1) {
  int idx = blockIdx.x * 256 + threadIdx.x;
  if (idx >= B_ * 32 * NT) return;
  int pos = idx % NT, r = idx / NT, cg = r & 31, b = r >> 5;
  const float* hb = hid + (size_t)b * 64 * NT + pos;
  float s0 = 0, u0 = 0, s1 = 0, u1 = 0;
  for (int i = 0; i < 64; i++) {
    float h = hb[(size_t)i * NT];
    s0 += h * W[(cg) * 64 + i];
    u0 += h * W[(cg + 64) * 64 + i];
    s1 += h * W[(cg + 32) * 64 + i];
    u1 += h * W[(cg + 96) * 64 + i];
  }
  g1[((size_t)b * 64 + cg) * NT + pos] =
      sigm(s0 + bias[cg]) * tanhf(u0 + bias[cg + 64]);
  g1[((size_t)b * 64 + cg + 32) * NT + pos] =
      sigm(s1 + bias[cg + 32]) * tanhf(u1 + bias[cg + 96]);
}

// ---------------- k5b: pyr2 gated ----------------
__global__ __launch_bounds__(256) void k5b_pyr2(const float* __restrict__ hid,
                                                const float* __restrict__ W,
                                                const float* __restrict__ bias,
                                                float* __restrict__ g2) {
  int idx = blockIdx.x * 256 + threadIdx.x;
  if (idx >= B_ * 32 * N_ * 4) return;
  int q = idx & 3, r = idx >> 2;
  int n = r % N_; r /= N_;
  int cg = r & 31, b = r >> 5;
  const float* hb = hid + (size_t)b * 64 * NT + n * 12 + 3 * q;
  float s0 = 0, u0 = 0, s1 = 0, u1 = 0;
  for (int i = 0; i < 64; i++) {
    const float* hh = hb + (size_t)i * NT;
#pragma unroll
    for (int k = 0; k < 3; k++) {
      float h = hh[k];
      s0 += h * W[(cg) * 192 + i * 3 + k];
      u0 += h * W[(cg + 64) * 192 + i * 3 + k];
      s1 += h * W[(cg + 32) * 192 + i * 3 + k];
      u1 += h * W[(cg + 96) * 192 + i * 3 + k];
    }
  }
  g2[(((size_t)b * 64 + cg) * N_ + n) * 4 + q] =
      sigm(s0 + bias[cg]) * tanhf(u0 + bias[cg + 64]);
  g2[(((size_t)b * 64 + cg + 32) * N_ + n) * 4 + q] =
      sigm(s1 + bias[cg + 32]) * tanhf(u1 + bias[cg + 96]);
}

// ---------------- k5c: pyr3 gated ----------------
__global__ __launch_bounds__(256) void k5c_pyr3(const float* __restrict__ hid,
                                                const float* __restrict__ W,
                                                const float* __restrict__ bias,
                                                float* __restrict__ g3) {
  int idx = blockIdx.x * 256 + threadIdx.x;
  if (idx >= B_ * 32 * N_ * 2) return;
  int q = idx & 1, r = idx >> 1;
  int n = r % N_; r /= N_;
  int cg = r & 31, b = r >> 5;
  const float* hb = hid + (size_t)b * 64 * NT + n * 12 + 6 * q;
  float s0 = 0, u0 = 0, s1 = 0, u1 = 0;
  for (int i = 0; i < 64; i++) {
    const float* hh = hb + (size_t)i * NT;
#pragma unroll
    for (int k = 0; k < 6; k++) {
      float h = hh[k];
      s0 += h * W[(cg) * 384 + i * 6 + k];
      u0 += h * W[(cg + 64) * 384 + i * 6 + k];
      s1 += h * W[(cg + 32) * 384 + i * 6 + k];
      u1 += h * W[(cg + 96) * 384 + i * 6 + k];
    }
  }
  g3[(((size_t)b * 64 + cg) * N_ + n) * 2 + q] =
      sigm(s0 + bias[cg]) * tanhf(u0 + bias[cg + 64]);
  g3[(((size_t)b * 64 + cg + 32) * N_ + n) * 2 + q] =
      sigm(s1 + bias[cg + 32]) * tanhf(u1 + bias[cg + 96]);
}

// ---------------- k5d: fusion conv + bn + residual bn ----------------
__global__ __launch_bounds__(256) void k5d_fuse(
    const float* __restrict__ g1, const float* __restrict__ g2, const float* __restrict__ g3,
    const float* __restrict__ W, const float* __restrict__ bias,
    const float* __restrict__ pg, const float* __restrict__ pb,
    const float* __restrict__ pm, const float* __restrict__ pv,
    const float* __restrict__ bg, const float* __restrict__ bb2,
    const float* __restrict__ bm2, const float* __restrict__ bv2,
    float* __restrict__ fus, float* __restrict__ x) {
  int idx = blockIdx.x * 256 + threadIdx.x;
  if (idx >= B_ * 16 * NT) return;
  int pos = idx % NT, r = idx / NT, og = r & 15, b = r >> 4;
  int n = pos / 12, t = pos - 12 * n;
  float a0 = 0, a1 = 0, a2 = 0, a3 = 0;
  const float* g1b = g1 + (size_t)b * 64 * NT + pos;
  for (int c = 0; c < 64; c++) {
    float v = g1b[(size_t)c * NT];
    a0 += v * W[(og) * 192 + c];
    a1 += v * W[(og + 16) * 192 + c];
    a2 += v * W[(og + 32) * 192 + c];
    a3 += v * W[(og + 48) * 192 + c];
  }
  float c4 = fminf(fmaxf((t - 1) * (1.f / 3.f), 0.f), 3.f);
  int q0 = (int)c4;
  float f4 = c4 - (float)q0;
  int q1 = min(q0 + 1, 3);
  const float* g2b = g2 + ((size_t)b * 64 * N_ + n) * 4;
  for (int c = 0; c < 64; c++) {
    float v = (1.f - f4) * g2b[c * (N_ * 4) + q0] + f4 * g2b[c * (N_ * 4) + q1];
    a0 += v * W[(og) * 192 + 64 + c];
    a1 += v * W[(og + 16) * 192 + 64 + c];
    a2 += v * W[(og + 32) * 192 + 64 + c];
    a3 += v * W[(og + 48) * 192 + 64 + c];
  }
  float f2 = fminf(fmaxf((2 * t - 5) * (1.f / 12.f), 0.f), 1.f);
  const float* g3b = g3 + ((size_t)b * 64 * N_ + n) * 2;
  for (int c = 0; c < 64; c++) {
    float v = (1.f - f2) * g3b[c * (N_ * 2)] + f2 * g3b[c * (N_ * 2) + 1];
    a0 += v * W[(og) * 192 + 128 + c];
    a1 += v * W[(og + 16) * 192 + 128 + c];
    a2 += v * W[(og + 32) * 192 + 128 + c];
    a3 += v * W[(og + 48) * 192 + 128 + c];
  }
  float accs[4] = {a0, a1, a2, a3};
#pragma unroll
  for (int k = 0; k < 4; k++) {
    int o = og + 16 * k;
    float y = accs[k] + bias[o];
    float s1 = pg[o] / sqrtf(pv[o] + 1e-5f);
    float fv = (y - pm[o]) * s1 + pb[o];
    size_t off = ((size_t)b * 64 + o) * NT + pos;
    fus[off] = fv;
    float xr = x[off];
    float s2 = bg[o] / sqrtf(bv2[o] + 1e-5f);
    x[off] = (fv + xr - bm2[o]) * s2 + bb2[o];
  }
}

// ---------------- k5e: skip conv at t=T-1 only ----------------
__global__ __launch_bounds__(256) void k5e_skip(const float* __restrict__ fus,
                                                const float* __restrict__ W,
                                                const float* __restrict__ bias,
                                                float* __restrict__ skip, int accum) {
  int idx = blockIdx.x * 256 + threadIdx.x;
  if (idx >= B_ * 128 * N_) return;
  int n = idx % N_, s = (idx / N_) & 127, b = idx / (N_ * 128);
  const float* fb = fus + (size_t)b * 64 * NT + n * 12 + 11;
  float a = bias[s];
  for (int c = 0; c < 64; c++) a += fb[(size_t)c * NT] * W[s * 64 + c];
  size_t o = ((size_t)b * 128 + s) * N_ + n;
  skip[o] = accum ? (skip[o] + a) : a;
}

// ---------------- k6: end MLP per (b,n) — fp32 output ----------------
__global__ __launch_bounds__(256) void k6_end(const float* __restrict__ skip,
                                              const float* __restrict__ w1,
                                              const float* __restrict__ b1,
                                              const float* __restrict__ w2,
                                              const float* __restrict__ b2,
                                              float* __restrict__ out) {
  __shared__ float sk[128];
  __shared__ float h[256];
  const int blk = blockIdx.x;
  const int b = blk / N_;
  const int n = blk - N_ * b;
  const int tid = threadIdx.x;
  if (tid < 128) sk[tid] = fmaxf(skip[((size_t)b * 128 + tid) * N_ + n], 0.f);
  __syncthreads();
  {
    float a = b1[tid];
    for (int s = 0; s < 128; s++) a += w1[tid * 128 + s] * sk[s];
    h[tid] = fmaxf(a, 0.f);
  }
  __syncthreads();
  if (tid < 12) {
    float a = b2[tid];
    for (int e = 0; e < 256; e++) a += w2[tid * 256 + e] * h[e];
    out[((size_t)b * 12 + tid) * N_ + n] = a;
  }
}

// ---------------- host ----------------
extern "C" void kernel_launch(void* const* d_in, const int* in_sizes, int n_in,
                              void* d_out, int out_size, void* d_ws, size_t ws_size,
                              hipStream_t stream) {
  (void)in_sizes; (void)n_in;
  if (ws_size < (size_t)44 * 1024 * 1024) {
    k_sentinel<<<(out_size + 255) / 256, 256, 0, stream>>>((float*)d_out, out_size);
    return;
  }
  const float* src = (const float*)d_in[0];
  const int* TE = (const int*)d_in[1];
  const float* sp = (const float*)d_in[2];
  const float* tp = (const float*)d_in[3];
  const float* SE = (const float*)d_in[4];
  const float* tmlp1_w = (const float*)d_in[5];
  const float* tmlp1_b = (const float*)d_in[6];
  const float* tmlp2_w = (const float*)d_in[7];
  const float* tmlp2_b = (const float*)d_in[8];
  const float* smlp1_w = (const float*)d_in[9];
  const float* smlp1_b = (const float*)d_in[10];
  const float* smlp2_w = (const float*)d_in[11];
  const float* smlp2_b = (const float*)d_in[12];
  const float* start_w = (const float*)d_in[13];
  const float* start_b = (const float*)d_in[14];
  const float* th1w = (const float*)d_in[15];
  const float* th1b = (const float*)d_in[16];
  const float* th2w = (const float*)d_in[17];
  const float* th2b = (const float*)d_in[18];
  const float* stw = (const float*)d_in[19];
  const float* stb = (const float*)d_in[20];
  const float* stg = (const float*)d_in[21];
  const float* stbb = (const float*)d_in[22];
  const float* stm = (const float*)d_in[23];
  const float* stv = (const float*)d_in[24];
  const float* p1w = (const float*)d_in[25];
  const float* p1b = (const float*)d_in[26];
  const float* p2w = (const float*)d_in[27];
  const float* p2b = (const float*)d_in[28];
  const float* p3w = (const float*)d_in[29];
  const float* p3b = (const float*)d_in[30];
  const float* pcw = (const float*)d_in[31];
  const float* pcb = (const float*)d_in[32];
  const float* pbg = (const float*)d_in[33];
  const float* pbb = (const float*)d_in[34];
  const float* pbm = (const float*)d_in[35];
  const float* pbv = (const float*)d_in[36];
  const float* skw = (const float*)d_in[37];
  const float* skb = (const float*)d_in[38];
  const float* bng = (const float*)d_in[39];
  const float* bnb = (const float*)d_in[40];
  const float* bnm = (const float*)d_in[41];
  const float* bnv = (const float*)d_in[42];
  const float* e1w = (const float*)d_in[43];
  const float* e1b = (const float*)d_in[44];
  const float* e2w = (const float*)d_in[45];
  const float* e2b = (const float*)d_in[46];

  float* ws = (float*)d_ws;
  float* coef = ws + 0;              // 2*8*66
  float* LsT  = ws + 8192;           // 325*328
  float* gA   = ws + 131072;         // aliased by fus
  float* gB   = ws + 2162688;        // aliased by g2/g3
  float* fus  = gA;
  float* g2   = gB;
  float* g3   = gB + 1048576;
  float* x    = ws + 4194304;        // [B,64,N,T]
  float* xst  = ws + 6291456;        // x_st; reused as g1
  float* hid  = ws + 8388608;        // hidden
  float* skipb= ws + 10485760;       // [B,128,N]

  k0_convert<<<(N_ * LSP + 255) / 256, 256, 0, stream>>>(sp, LsT);
  k1_embed<<<1, 256, 0, stream>>>(TE, SE, tmlp1_w, tmlp1_b, tmlp2_w, tmlp2_b,
                                  smlp1_w, smlp1_b, smlp2_w, smlp2_b,
                                  th1w, th1b, th2w, th2b, coef);
  k2_start<<<(B_ * C_ * NT + 255) / 256, 256, 0, stream>>>(src, start_w, start_b, x);

  for (int l = 0; l < 2; l++) {
    k3_basis<<<512, 512, 0, stream>>>(x, LsT, tp, coef + l * 528, xst);
    k4_stmlp<<<(B_ * 16 * NT + 255) / 256, 256, 0, stream>>>(
        x, xst, stw + l * 8192, stb + l * 64, stg + l * 64, stbb + l * 64,
        stm + l * 64, stv + l * 64, hid);
    k5a_pyr1<<<(B_ * 32 * NT + 255) / 256, 256, 0, stream>>>(
        hid, p1w + l * 8192, p1b + l * 128, xst /* g1 */);
    k5b_pyr2<<<(B_ * 32 * N_ * 4 + 255) / 256, 256, 0, stream>>>(
        hid, p2w + l * 24576, p2b + l * 128, g2);
    k5c_pyr3<<<(B_ * 32 * N_ * 2 + 255) / 256, 256, 0, stream>>>(
        hid, p3w + l * 49152, p3b + l * 128, g3);
    k5d_fuse<<<(B_ * 16 * NT + 255) / 256, 256, 0, stream>>>(
        xst /* g1 */, g2, g3, pcw + l * 12288, pcb + l * 64,
        pbg + l * 64, pbb + l * 64, pbm + l * 64, pbv + l * 64,
        bng + l * 64, bnb + l * 64, bnm + l * 64, bnv + l * 64, fus, x);
    k5e_skip<<<(B_ * 128 * N_ + 255) / 256, 256, 0, stream>>>(
        fus, skw + l * 8192, skb + l * 128, skipb, l);
  }
  k6_end<<<B_ * N_, 256, 0, stream>>>(skipb, e1w, e1b, e2w, e2b, (float*)d_out);
}

// Round 8
// 1665.355 us; speedup vs baseline: 1.8993x; 1.0829x over previous
//
#include <hip/hip_runtime.h>
#include <hip/hip_bf16.h>
#include <math.h>

// ---------------- problem constants ----------------
#define B_   8
#define T_   12
#define N_   325
#define C_   64
#define NT   3900     // N_*T_
#define LSP  328      // padded row stride of transposed sp matrix

__device__ __forceinline__ float sigm(float x) { return 1.f / (1.f + expf(-x)); }

// 512-thread (8-wave) multi-value reduction; ONE barrier (caller ping-pongs redb)
__device__ __forceinline__ void redN(float* v, int nv, float (*redb)[4], int tid) {
#pragma unroll
  for (int off = 1; off < 64; off <<= 1) {
    for (int i = 0; i < nv; i++) v[i] += __shfl_xor(v[i], off, 64);
  }
  if ((tid & 63) == 0) {
    for (int i = 0; i < nv; i++) redb[tid >> 6][i] = v[i];
  }
  __syncthreads();
  for (int i = 0; i < nv; i++) {
    float s = 0.f;
#pragma unroll
    for (int w = 0; w < 8; w++) s += redb[w][i];
    v[i] = s;
  }
}

// ---------------- sentinel (ws too small diagnostic) ----------------
__global__ __launch_bounds__(256) void k_sentinel(float* out, int n) {
  int i = blockIdx.x * 256 + threadIdx.x;
  if (i < n) out[i] = 7.0f;
}

// ---------------- k0: transpose sp (padded) ----------------
__global__ __launch_bounds__(256) void k0_convert(const float* __restrict__ sp,
                                                  float* __restrict__ LsT) {
  int idx = blockIdx.x * 256 + threadIdx.x;
  if (idx < N_ * LSP) {
    int m = idx / LSP, n = idx - m * LSP;
    LsT[idx] = (n < N_) ? sp[n * N_ + m] : 0.f;   // LsT[m][n] = Ls[n][m]
  }
}

// ---------------- k1: embeddings + theta coefficients ----------------
__global__ __launch_bounds__(256) void k1_embed(
    const int* __restrict__ TE, const float* __restrict__ SE,
    const float* __restrict__ w1, const float* __restrict__ b1,
    const float* __restrict__ w2, const float* __restrict__ b2,
    const float* __restrict__ sw1, const float* __restrict__ sb1,
    const float* __restrict__ sw2, const float* __restrict__ sb2,
    const float* __restrict__ t1w, const float* __restrict__ t1b,
    const float* __restrict__ t2w, const float* __restrict__ t2b,
    float* __restrict__ coef) {
  __shared__ float te2[8][10][12];
  __shared__ float ste[8][5][10];
  __shared__ float se1[5][10];
  __shared__ float se2[5][10];
  __shared__ float th[8][6][10];
  __shared__ int te64;
  const int tid = threadIdx.x;
  if (tid == 0) {
    int nz = 0;
    for (int k2 = 0; k2 < 96; k2++) nz += (TE[2 * k2 + 1] != 0) ? 1 : 0;
    te64 = (nz == 0) ? 1 : 0;
  }
  __syncthreads();
  for (int idx = tid; idx < 960; idx += 256) {
    int t = idx % 12, o = (idx / 12) % 10, b = idx / 120;
    int q = (b * 12 + t) * 2;
    int d = (te64 ? TE[2 * q] : TE[q]) % 7;
    int h = (te64 ? TE[2 * q + 2] : TE[q + 1]) % 288;
    float v = w1[o * 295 + d] + w1[o * 295 + 7 + h] + b1[o];
    te2[b][o][t] = fmaxf(v, 0.f);
  }
  __syncthreads();
  for (int idx = tid; idx < 400; idx += 256) {
    int s = idx % 10, o = (idx / 10) % 5, b = idx / 50;
    float a = b2[o];
    for (int t = 0; t < 12; t++) a += te2[b][s][t] * w2[o * 12 + t];
    ste[b][o][s] = fmaxf(a, 0.f);
  }
  if (tid < 50) {
    int o = tid / 10, j = tid % 10;
    float a = sb1[o];
    for (int n = 0; n < N_; n++) a += sw1[o * N_ + n] * SE[n * 10 + j];
    se1[o][j] = fmaxf(a, 0.f);
  }
  __syncthreads();
  if (tid < 50) {
    int t = tid / 10, s = tid % 10;
    float a = sb2[s];
    for (int j = 0; j < 10; j++) a += sw2[s * 10 + j] * se1[t][j];
    se2[t][s] = fmaxf(a, 0.f);
  }
  __syncthreads();
  for (int idx = tid; idx < 400; idx += 256) {
    int s = idx % 10, o = (idx / 10) % 5, b = idx / 50;
    ste[b][o][s] = fmaxf(se2[o][s] + ste[b][o][s], 0.f);
  }
  __syncthreads();
  for (int l = 0; l < 2; l++) {
    for (int idx = tid; idx < 480; idx += 256) {
      int s = idx % 10, q = (idx / 10) % 6, b = idx / 60;
      float a = t1b[l * 6 + q];
      for (int t = 0; t < 5; t++) a += ste[b][t][s] * t1w[(l * 6 + q) * 5 + t];
      th[b][q][s] = a;
    }
    __syncthreads();
    for (int idx = tid; idx < 528; idx += 256) {
      int q = idx % 6, p = (idx / 6) % 11, b = idx / 66;
      float a = t2b[l * 11 + p];
      for (int s = 0; s < 10; s++) a += th[b][q][s] * t2w[(l * 11 + p) * 10 + s];
      coef[(l * 8 + b) * 66 + q * 11 + p] = fmaxf(a, 0.f);
    }
    __syncthreads();
  }
}

// ---------------- k2: start 1x1 conv ----------------
__global__ __launch_bounds__(256) void k2_start(const float* __restrict__ src,
                                                const float* __restrict__ w,
                                                const float* __restrict__ bia,
                                                float* __restrict__ x) {
  int idx = blockIdx.x * 256 + threadIdx.x;
  if (idx >= B_ * C_ * NT) return;
  int pos = idx % NT, r = idx / NT, c = r & 63, b = r >> 6;
  int n = pos / 12, t = pos - 12 * n;
  float s = src[(b * 12 + t) * N_ + n];
  x[idx] = s * w[c] + bia[c];
}

// ---------------- k3: fused basis recursion + x_st accumulation ----------------
__global__ __launch_bounds__(512, 4) void k3_basis(
    const float* __restrict__ x, const float* __restrict__ LsT,
    const float* __restrict__ tp, const float* __restrict__ coef,
    float* __restrict__ xst) {
  __shared__ float sb[2][3904];
  __shared__ float sred[2][8][4];
  const int tid = threadIdx.x;
  const int bc = blockIdx.x;
  const float* cf = coef + (bc >> 6) * 66;
  const float* xs = x + (size_t)bc * NT;
  float* xo = xst + (size_t)bc * NT;

  const int pr = tid / 3, tb = tid - 3 * pr;
  const int n0 = 2 * pr, t0 = 4 * tb;
  const bool actS = (tid < 489);
  const bool r1 = actS && (n0 + 1 < N_);
  const int e0 = n0 * 12 + t0;

  const bool actT = (tid < N_);
  const int rowOff = tid * 12;

  float w[11];
#pragma unroll
  for (int k = 0; k < 11; k++) w[k] = tp[k * 12 + k + 1];

  float last[12], sec[12], acc[12], rr[12];

  int p = 0, m = 0, spc = 0;

  {
    float np = 0.f;
#pragma unroll
    for (int u = 0; u < 12; u++) rr[u] = 0.f;
    if (actT) {
      const float4 a = *(const float4*)(xs + rowOff);
      const float4 b4 = *(const float4*)(xs + rowOff + 4);
      const float4 c4 = *(const float4*)(xs + rowOff + 8);
      rr[0] = a.x; rr[1] = a.y; rr[2] = a.z; rr[3] = a.w;
      rr[4] = b4.x; rr[5] = b4.y; rr[6] = b4.z; rr[7] = b4.w;
      rr[8] = c4.x; rr[9] = c4.y; rr[10] = c4.z; rr[11] = c4.w;
#pragma unroll
      for (int u = 0; u < 12; u++) np += rr[u] * rr[u];
    }
    p ^= 1; redN(&np, 1, sred[p], tid);
    const float inv = 1.f / fmaxf(sqrtf(np), 1e-8f);
    const float c0 = cf[m]; m++;
#pragma unroll
    for (int u = 0; u < 12; u++) {
      last[u] = rr[u] * inv;
      acc[u] = c0 * last[u];
      sec[u] = 0.f;
    }
    if (actT) {
      float4 wv;
      wv.x = last[0]; wv.y = last[1]; wv.z = last[2]; wv.w = last[3];
      *(float4*)&sb[0][rowOff] = wv;
      wv.x = last[4]; wv.y = last[5]; wv.z = last[6]; wv.w = last[7];
      *(float4*)&sb[0][rowOff + 4] = wv;
      wv.x = last[8]; wv.y = last[9]; wv.z = last[10]; wv.w = last[11];
      *(float4*)&sb[0][rowOff + 8] = wv;
    }
    __syncthreads();
  }

  for (int i = 0; i <= 10; i++) {
    if (i > 0) {
      const int sps = 1 - spc;
      const bool hasSec = (i >= 2);
      float v3[3] = {0.f, 0.f, 0.f};
      float rr0[4], rr1[4], l0[4], l1[4], s0[4], s1[4];
#pragma unroll
      for (int j = 0; j < 4; j++) {
        rr0[j] = 0.f; rr1[j] = 0.f; l0[j] = 0.f; l1[j] = 0.f;
        s0[j] = 0.f; s1[j] = 0.f;
      }
      if (actS) {
        const float* lpc = LsT + n0;
        const float* sc = &sb[spc][t0];
#pragma unroll 4
        for (int mm = 0; mm < N_; mm++) {
          const float2 a = *(const float2*)(lpc + mm * LSP);
          const float4 mr = *(const float4*)(sc + mm * 12);
          rr0[0] += a.x * mr.x; rr0[1] += a.x * mr.y;
          rr0[2] += a.x * mr.z; rr0[3] += a.x * mr.w;
          rr1[0] += a.y * mr.x; rr1[1] += a.y * mr.y;
          rr1[2] += a.y * mr.z; rr1[3] += a.y * mr.w;
        }
        {
          const float4 q = *(const float4*)&sb[spc][e0];
          l0[0] = q.x; l0[1] = q.y; l0[2] = q.z; l0[3] = q.w;
        }
        if (r1) {
          const float4 q = *(const float4*)&sb[spc][e0 + 12];
          l1[0] = q.x; l1[1] = q.y; l1[2] = q.z; l1[3] = q.w;
        }
#pragma unroll
        for (int j = 0; j < 4; j++) v3[0] += rr0[j] * l0[j] + rr1[j] * l1[j];
        if (hasSec) {
          {
            const float4 q = *(const float4*)&sb[sps][e0];
            s0[0] = q.x; s0[1] = q.y; s0[2] = q.z; s0[3] = q.w;
          }
          if (r1) {
            const float4 q = *(const float4*)&sb[sps][e0 + 12];
            s1[0] = q.x; s1[1] = q.y; s1[2] = q.z; s1[3] = q.w;
          }
#pragma unroll
          for (int j = 0; j < 4; j++) {
            v3[1] += rr0[j] * s0[j] + rr1[j] * s1[j];
            v3[2] += l0[j] * s0[j] + l1[j] * s1[j];
          }
        }
      }
      p ^= 1;
      if (hasSec) redN(v3, 3, sred[p], tid); else redN(v3, 1, sred[p], tid);
      const float d1 = v3[0];
      const float d2 = hasSec ? (v3[1] - d1 * v3[2]) : 0.f;
      float np = 0.f;
      if (actS) {
#pragma unroll
        for (int j = 0; j < 4; j++) {
          rr0[j] -= d1 * l0[j] + d2 * s0[j];
          rr1[j] -= d1 * l1[j] + d2 * s1[j];
          np += rr0[j] * rr0[j] + rr1[j] * rr1[j];
        }
      }
      p ^= 1; redN(&np, 1, sred[p], tid);
      const float inv = 1.f / fmaxf(sqrtf(np), 1e-8f);
      const float cs = cf[m]; m++;
      if (actS) {
        float4 wv;
        wv.x = rr0[0] * inv; wv.y = rr0[1] * inv;
        wv.z = rr0[2] * inv; wv.w = rr0[3] * inv;
        *(float4*)&sb[sps][e0] = wv;
        if (r1) {
          wv.x = rr1[0] * inv; wv.y = rr1[1] * inv;
          wv.z = rr1[2] * inv; wv.w = rr1[3] * inv;
          *(float4*)&sb[sps][e0 + 12] = wv;
        }
      }
      spc = sps;
      __syncthreads();
      if (actT) {
        const float4 a = *(const float4*)&sb[spc][rowOff];
        const float4 b4 = *(const float4*)&sb[spc][rowOff + 4];
        const float4 c4 = *(const float4*)&sb[spc][rowOff + 8];
        last[0] = a.x; last[1] = a.y; last[2] = a.z; last[3] = a.w;
        last[4] = b4.x; last[5] = b4.y; last[6] = b4.z; last[7] = b4.w;
        last[8] = c4.x; last[9] = c4.y; last[10] = c4.z; last[11] = c4.w;
#pragma unroll
        for (int u = 0; u < 12; u++) {
          acc[u] += cs * last[u];
          sec[u] = 0.f;
        }
      }
    }
    for (int j5 = 0; j5 < 5; j5++) {
      float v3[3] = {0.f, 0.f, 0.f};
      if (actT) {
#pragma unroll
        for (int u = 0; u < 12; u++) {
          float r = 0.f;
          if (u > 0) r += last[u - 1] * w[u - 1];
          if (u < 11) r += last[u + 1] * w[u];
          rr[u] = r;
          v3[0] += r * last[u];
          v3[1] += r * sec[u];
          v3[2] += last[u] * sec[u];
        }
      }
      p ^= 1; redN(v3, 3, sred[p], tid);
      const float d1 = v3[0];
      const float d2 = v3[1] - d1 * v3[2];
      float np = 0.f;
      if (actT) {
#pragma unroll
        for (int u = 0; u < 12; u++) {
          rr[u] -= d1 * last[u] + d2 * sec[u];
          np += rr[u] * rr[u];
        }
      }
      p ^= 1; redN(&np, 1, sred[p], tid);
      const float inv = 1.f / fmaxf(sqrtf(np), 1e-8f);
      const float c = cf[m]; m++;
      if (actT) {
#pragma unroll
        for (int u = 0; u < 12; u++) {
          const float v = rr[u] * inv;
          sec[u] = last[u];
          last[u] = v;
          acc[u] += c * v;
        }
      }
    }
  }
  if (actT) {
    float4 wv;
    wv.x = acc[0]; wv.y = acc[1]; wv.z = acc[2]; wv.w = acc[3];
    *(float4*)(xo + rowOff) = wv;
    wv.x = acc[4]; wv.y = acc[5]; wv.z = acc[6]; wv.w = acc[7];
    *(float4*)(xo + rowOff + 4) = wv;
    wv.x = acc[8]; wv.y = acc[9]; wv.z = acc[10]; wv.w = acc[11];
    *(float4*)(xo + rowOff + 8) = wv;
  }
}

// ---------------- k45: fused layer body (st_mlp..skip), one block per (b,n) --
__global__ __launch_bounds__(256) void k45_layer(
    float* __restrict__ x, const float* __restrict__ xst,
    const float* __restrict__ stw, const float* __restrict__ stb,
    const float* __restrict__ stg, const float* __restrict__ stbb,
    const float* __restrict__ stm, const float* __restrict__ stv,
    const float* __restrict__ p1w, const float* __restrict__ p1b,
    const float* __restrict__ p2w, const float* __restrict__ p2b,
    const float* __restrict__ p3w, const float* __restrict__ p3b,
    const float* __restrict__ pcw, const float* __restrict__ pcb,
    const float* __restrict__ pbg, const float* __restrict__ pbb,
    const float* __restrict__ pbm, const float* __restrict__ pbv,
    const float* __restrict__ bng, const float* __restrict__ bnb,
    const float* __restrict__ bnm, const float* __restrict__ bnv,
    const float* __restrict__ skw, const float* __restrict__ skb,
    float* __restrict__ skipb, int accum) {
  __shared__ float xr[64][12];   // residual, later new-x
  __shared__ float xq[64][12];   // x_st
  __shared__ float hd[64][12];   // hidden
  __shared__ float g1s[64][12];
  __shared__ float g2s[64][4];
  __shared__ float g3s[64][2];
  __shared__ float fu[64][12];
  const int tid = threadIdx.x;
  const int bid = blockIdx.x;
  const int b = bid / N_, n = bid - N_ * b;
  const size_t base = ((size_t)b * 64) * NT + n * 12;
  // load x, xst (192 float4 each)
  if (tid < 192) {
    int c = tid / 3, ch = tid - 3 * (tid / 3);
    *(float4*)&xr[c][ch * 4] = *(const float4*)(x + base + (size_t)c * NT + ch * 4);
    *(float4*)&xq[c][ch * 4] = *(const float4*)(xst + base + (size_t)c * NT + ch * 4);
  }
  __syncthreads();
  // hidden = bn(st_mlp(concat[x, xst]))
  for (int idx = tid; idx < 768; idx += 256) {
    int o = idx / 12, t = idx - 12 * o;
    float a = 0.f;
    const float* w0 = stw + o * 128;
    for (int i = 0; i < 64; i++) a += xr[i][t] * w0[i];
    for (int i = 0; i < 64; i++) a += xq[i][t] * w0[64 + i];
    a += stb[o];
    float sc = stg[o] / sqrtf(stv[o] + 1e-5f);
    hd[o][t] = (a - stm[o]) * sc + stbb[o];
  }
  __syncthreads();
  // gated pyramids
  for (int idx = tid; idx < 1152; idx += 256) {
    if (idx < 768) {
      int o = idx / 12, t = idx - 12 * o;
      float s = 0.f, u = 0.f;
      const float* wsr = p1w + o * 64;
      const float* wur = p1w + (o + 64) * 64;
      for (int i = 0; i < 64; i++) { float h = hd[i][t]; s += h * wsr[i]; u += h * wur[i]; }
      g1s[o][t] = sigm(s + p1b[o]) * tanhf(u + p1b[o + 64]);
    } else if (idx < 1024) {
      int r = idx - 768; int o = r >> 2, q = r & 3;
      float s = 0.f, u = 0.f;
      const float* wsr = p2w + o * 192;
      const float* wur = p2w + (o + 64) * 192;
      for (int i = 0; i < 64; i++)
#pragma unroll
        for (int k = 0; k < 3; k++) {
          float h = hd[i][3 * q + k];
          s += h * wsr[i * 3 + k]; u += h * wur[i * 3 + k];
        }
      g2s[o][q] = sigm(s + p2b[o]) * tanhf(u + p2b[o + 64]);
    } else {
      int r = idx - 1024; int o = r >> 1, q = r & 1;
      float s = 0.f, u = 0.f;
      const float* wsr = p3w + o * 384;
      const float* wur = p3w + (o + 64) * 384;
      for (int i = 0; i < 64; i++)
#pragma unroll
        for (int k = 0; k < 6; k++) {
          float h = hd[i][6 * q + k];
          s += h * wsr[i * 6 + k]; u += h * wur[i * 6 + k];
        }
      g3s[o][q] = sigm(s + p3b[o]) * tanhf(u + p3b[o + 64]);
    }
  }
  __syncthreads();
  // fusion conv + pyr bn ; residual bn -> new x (into xr)
  for (int idx = tid; idx < 768; idx += 256) {
    int o = idx / 12, t = idx - 12 * o;
    float a = 0.f;
    const float* w0 = pcw + o * 192;
    for (int c = 0; c < 64; c++) a += g1s[c][t] * w0[c];
    float c4 = fminf(fmaxf((t - 1) * (1.f / 3.f), 0.f), 3.f);
    int q0 = (int)c4;
    float f4 = c4 - (float)q0;
    int q1 = min(q0 + 1, 3);
    for (int c = 0; c < 64; c++) {
      float v = (1.f - f4) * g2s[c][q0] + f4 * g2s[c][q1];
      a += v * w0[64 + c];
    }
    float f2 = fminf(fmaxf((2 * t - 5) * (1.f / 12.f), 0.f), 1.f);
    for (int c = 0; c < 64; c++) {
      float v = (1.f - f2) * g3s[c][0] + f2 * g3s[c][1];
      a += v * w0[128 + c];
    }
    a += pcb[o];
    float s1 = pbg[o] / sqrtf(pbv[o] + 1e-5f);
    float fv = (a - pbm[o]) * s1 + pbb[o];
    fu[o][t] = fv;
    float s2 = bng[o] / sqrtf(bnv[o] + 1e-5f);
    xr[o][t] = (fv + xr[o][t] - bnm[o]) * s2 + bnb[o];
  }
  __syncthreads();
  // write new x (vectorized)
  if (tid < 192) {
    int c = tid / 3, ch = tid - 3 * (tid / 3);
    *(float4*)(x + base + (size_t)c * NT + ch * 4) = *(float4*)&xr[c][ch * 4];
  }
  // skip conv at t = 11
  if (tid < 128) {
    float a = skb[tid];
    const float* wr = skw + tid * 64;
    for (int c = 0; c < 64; c++) a += fu[c][11] * wr[c];
    size_t o = ((size_t)b * 128 + tid) * N_ + n;
    skipb[o] = accum ? (skipb[o] + a) : a;
  }
}

// ---------------- k6: end MLP per (b,n) — fp32 output ----------------
__global__ __launch_bounds__(256) void k6_end(const float* __restrict__ skip,
                                              const float* __restrict__ w1,
                                              const float* __restrict__ b1,
                                              const float* __restrict__ w2,
                                              const float* __restrict__ b2,
                                              float* __restrict__ out) {
  __shared__ float sk[128];
  __shared__ float h[256];
  const int blk = blockIdx.x;
  const int b = blk / N_;
  const int n = blk - N_ * b;
  const int tid = threadIdx.x;
  if (tid < 128) sk[tid] = fmaxf(skip[((size_t)b * 128 + tid) * N_ + n], 0.f);
  __syncthreads();
  {
    float a = b1[tid];
    for (int s = 0; s < 128; s++) a += w1[tid * 128 + s] * sk[s];
    h[tid] = fmaxf(a, 0.f);
  }
  __syncthreads();
  if (tid < 12) {
    float a = b2[tid];
    for (int e = 0; e < 256; e++) a += w2[tid * 256 + e] * h[e];
    out[((size_t)b * 12 + tid) * N_ + n] = a;
  }
}

// ---------------- host ----------------
extern "C" void kernel_launch(void* const* d_in, const int* in_sizes, int n_in,
                              void* d_out, int out_size, void* d_ws, size_t ws_size,
                              hipStream_t stream) {
  (void)in_sizes; (void)n_in;
  if (ws_size < (size_t)44 * 1024 * 1024) {
    k_sentinel<<<(out_size + 255) / 256, 256, 0, stream>>>((float*)d_out, out_size);
    return;
  }
  const float* src = (const float*)d_in[0];
  const int* TE = (const int*)d_in[1];
  const float* sp = (const float*)d_in[2];
  const float* tp = (const float*)d_in[3];
  const float* SE = (const float*)d_in[4];
  const float* tmlp1_w = (const float*)d_in[5];
  const float* tmlp1_b = (const float*)d_in[6];
  const float* tmlp2_w = (const float*)d_in[7];
  const float* tmlp2_b = (const float*)d_in[8];
  const float* smlp1_w = (const float*)d_in[9];
  const float* smlp1_b = (const float*)d_in[10];
  const float* smlp2_w = (const float*)d_in[11];
  const float* smlp2_b = (const float*)d_in[12];
  const float* start_w = (const float*)d_in[13];
  const float* start_b = (const float*)d_in[14];
  const float* th1w = (const float*)d_in[15];
  const float* th1b = (const float*)d_in[16];
  const float* th2w = (const float*)d_in[17];
  const float* th2b = (const float*)d_in[18];
  const float* stw = (const float*)d_in[19];
  const float* stb = (const float*)d_in[20];
  const float* stg = (const float*)d_in[21];
  const float* stbb = (const float*)d_in[22];
  const float* stm = (const float*)d_in[23];
  const float* stv = (const float*)d_in[24];
  const float* p1w = (const float*)d_in[25];
  const float* p1b = (const float*)d_in[26];
  const float* p2w = (const float*)d_in[27];
  const float* p2b = (const float*)d_in[28];
  const float* p3w = (const float*)d_in[29];
  const float* p3b = (const float*)d_in[30];
  const float* pcw = (const float*)d_in[31];
  const float* pcb = (const float*)d_in[32];
  const float* pbg = (const float*)d_in[33];
  const float* pbb = (const float*)d_in[34];
  const float* pbm = (const float*)d_in[35];
  const float* pbv = (const float*)d_in[36];
  const float* skw = (const float*)d_in[37];
  const float* skb = (const float*)d_in[38];
  const float* bng = (const float*)d_in[39];
  const float* bnb = (const float*)d_in[40];
  const float* bnm = (const float*)d_in[41];
  const float* bnv = (const float*)d_in[42];
  const float* e1w = (const float*)d_in[43];
  const float* e1b = (const float*)d_in[44];
  const float* e2w = (const float*)d_in[45];
  const float* e2b = (const float*)d_in[46];

  float* ws = (float*)d_ws;
  float* coef = ws + 0;              // 2*8*66
  float* LsT  = ws + 8192;           // 325*328
  float* x    = ws + 4194304;        // [B,64,N,T]
  float* xst  = ws + 6291456;        // x_st
  float* skipb= ws + 10485760;       // [B,128,N]

  k0_convert<<<(N_ * LSP + 255) / 256, 256, 0, stream>>>(sp, LsT);
  k1_embed<<<1, 256, 0, stream>>>(TE, SE, tmlp1_w, tmlp1_b, tmlp2_w, tmlp2_b,
                                  smlp1_w, smlp1_b, smlp2_w, smlp2_b,
                                  th1w, th1b, th2w, th2b, coef);
  k2_start<<<(B_ * C_ * NT + 255) / 256, 256, 0, stream>>>(src, start_w, start_b, x);

  for (int l = 0; l < 2; l++) {
    k3_basis<<<512, 512, 0, stream>>>(x, LsT, tp, coef + l * 528, xst);
    k45_layer<<<B_ * N_, 256, 0, stream>>>(
        x, xst,
        stw + l * 8192, stb + l * 64, stg + l * 64, stbb + l * 64,
        stm + l * 64, stv + l * 64,
        p1w + l * 8192, p1b + l * 128,
        p2w + l * 24576, p2b + l * 128,
        p3w + l * 49152, p3b + l * 128,
        pcw + l * 12288, pcb + l * 64,
        pbg + l * 64, pbb + l * 64, pbm + l * 64, pbv + l * 64,
        bng + l * 64, bnb + l * 64, bnm + l * 64, bnv + l * 64,
        skw + l * 8192, skb + l * 128,
        skipb, l);
  }
  k6_end<<<B_ * N_, 256, 0, stream>>>(skipb, e1w, e1b, e2w, e2b, (float*)d_out);
}